// Round 11
// baseline (1632.293 us; speedup 1.0000x reference)
//
#include <hip/hip_runtime.h>

// Problem dims (fixed by reference)
#define NN 49152
#define EHN 8192
#define MM (NN + EHN)       // 57344
#define FD 256
#define DD 256
#define NHEADS 8
#define DHEAD 32
#define CHK 1024
#define NEN (10 * NN)       // 491520
#define NEM (10 * MM)       // 573440
#define ROWS_TOT (4 * NN + 2 * MM)   // 311296
#define ETOT (4 * NEN + 2 * NEM)     // 3,112,960

typedef __bf16 bf16x8 __attribute__((ext_vector_type(8)));
typedef unsigned short u16x8 __attribute__((ext_vector_type(8)));
typedef float f32x4 __attribute__((ext_vector_type(4)));

static __device__ __forceinline__ unsigned short f2bf(float f) {
  unsigned int u = __float_as_uint(f);
  unsigned int r = (u + 0x7FFFu + ((u >> 16) & 1u)) >> 16;
  return (unsigned short)r;
}
static __device__ __forceinline__ float bf2f(unsigned short u) {
  return __uint_as_float((unsigned int)u << 16);
}
static __device__ __forceinline__ unsigned int cvtpk(float a, float b) {
  unsigned int r;
  asm("v_cvt_pk_bf16_f32 %0, %1, %2" : "=v"(r) : "v"(a), "v"(b));
  return r;
}
static __device__ __forceinline__ float max3f(float a, float b, float c) {
  return fmaxf(fmaxf(a, b), c);   // clang fuses to v_max3_f32
}

// ---------------- weight prep ----------------
struct CastJobs {
  const float* src[8];
  unsigned short* dst[8];
  int trans[8];
};
__global__ __launch_bounds__(256) void cast_w8_kernel(CastJobs jobs)
{
  int job = blockIdx.x >> 8;
  int i = (blockIdx.x & 255) * 256 + threadIdx.x;
  int n = i >> 8, k = i & 255;
  const float* src = jobs.src[job];
  float f = jobs.trans[job] ? src[(size_t)k * 256 + n] : src[i];
  jobs.dst[job][i] = f2bf(f);
}

__global__ __launch_bounds__(256) void combine_w_kernel(
    const float* __restrict__ Bw, const float* __restrict__ Aw,
    const float* __restrict__ ab, const float* __restrict__ bb,
    unsigned short* __restrict__ Wc, float* __restrict__ bc, float fscale)
{
  int n = blockIdx.x, t = threadIdx.x;
  __shared__ float shB[256];
  __shared__ float red[256];
  shB[t] = Bw[n * 256 + t];
  __syncthreads();
  float acc = 0.0f;
  #pragma unroll 8
  for (int j = 0; j < 256; ++j) acc += shB[j] * Aw[j * 256 + t];
  Wc[n * 256 + t] = f2bf(acc * fscale);
  red[t] = shB[t] * ab[t];
  __syncthreads();
  for (int off = 128; off; off >>= 1) {
    if (t < off) red[t] += red[t + off];
    __syncthreads();
  }
  if (t == 0) bc[n] = (red[0] + bb[n]) * fscale;
}

__global__ __launch_bounds__(256) void mm256f_kernel(
    const float* __restrict__ A, const float* __restrict__ B,
    float* __restrict__ C)
{
  int n = blockIdx.x, t = threadIdx.x;
  __shared__ float sa[256];
  sa[t] = A[n * 256 + t];
  __syncthreads();
  float acc = 0.0f;
  #pragma unroll 8
  for (int j = 0; j < 256; ++j) acc += sa[j] * B[j * 256 + t];
  C[n * 256 + t] = acc;
}

__global__ __launch_bounds__(256) void mm256b_kernel(
    const float* __restrict__ A, const float* __restrict__ B,
    unsigned short* __restrict__ W, float fs)
{
  int n = blockIdx.x, t = threadIdx.x;
  __shared__ float sa[256];
  sa[t] = A[n * 256 + t];
  __syncthreads();
  float acc = 0.0f;
  #pragma unroll 8
  for (int j = 0; j < 256; ++j) acc += sa[j] * B[j * 256 + t];
  W[n * 256 + t] = f2bf(acc * fs);
}

__global__ __launch_bounds__(256) void mv256_kernel(
    const float* __restrict__ W, const float* __restrict__ v,
    const float* __restrict__ add, float* __restrict__ outv, float fs)
{
  int t = threadIdx.x;
  __shared__ float sv[256];
  sv[t] = v[t];
  __syncthreads();
  float acc = 0.0f;
  #pragma unroll 8
  for (int k = 0; k < 256; ++k) acc += W[t * 256 + k] * sv[k];
  if (add) acc += add[t];
  outv[t] = fs * acc;
}

// ---------------- batched bf16-MFMA GEMM (3 jobs, bf16 out) ----------------
struct Gemm3 {
  const void* A[3];
  const unsigned short* W[3];
  const float* c0[3];
  const float* rs[3];
  const float* cvec[3];
  unsigned short* out[3];
  int bs1, bs2, btot;
};
template<int ABF>
__global__ __launch_bounds__(256) void gemm3_kernel(Gemm3 g)
{
  const int b = blockIdx.x;
  const int j = (b >= g.bs2) ? 2 : (b >= g.bs1 ? 1 : 0);
  const int bm = (b - (j == 2 ? g.bs2 : j == 1 ? g.bs1 : 0)) * 64;
  const void* Ain = g.A[j];
  const unsigned short* Wt = g.W[j];

  __shared__ __align__(16) char sA[2][4096];
  __shared__ __align__(16) char sB[2][16384];
  const int tid = threadIdx.x, lane = tid & 63, wid = tid >> 6;
  const int l15 = lane & 15, l4 = lane >> 4;

  f32x4 acc[16] = {};
  const int ar = tid >> 2, akq = (tid & 3) * 8;
  const int bn = tid;

  float4 fa0, fa1;
  u16x8 ua;
  u16x8 rb0, rb1, rb2, rb3;
  auto stage_load = [&](int k0) {
    if (ABF) {
      ua = *(const u16x8*)((const unsigned short*)Ain +
                           (size_t)(bm + ar) * 256 + k0 + akq);
    } else {
      const float* ap = (const float*)Ain + (size_t)(bm + ar) * 256 + k0 + akq;
      fa0 = *(const float4*)ap;
      fa1 = *(const float4*)(ap + 4);
    }
    const unsigned short* bp = Wt + (size_t)bn * 256 + k0;
    rb0 = *(const u16x8*)bp;        rb1 = *(const u16x8*)(bp + 8);
    rb2 = *(const u16x8*)(bp + 16); rb3 = *(const u16x8*)(bp + 24);
  };
  auto stage_write = [&](int buf) {
    u16x8 va;
    if (ABF) {
      va = ua;
    } else {
      va[0] = f2bf(fa0.x); va[1] = f2bf(fa0.y); va[2] = f2bf(fa0.z); va[3] = f2bf(fa0.w);
      va[4] = f2bf(fa1.x); va[5] = f2bf(fa1.y); va[6] = f2bf(fa1.z); va[7] = f2bf(fa1.w);
    }
    int aa = ((ar << 6) + (akq << 1)) ^ ((ar & 7) << 4);
    *(u16x8*)(sA[buf] + aa) = va;
    int bb = (bn << 6) ^ ((bn & 7) << 4);
    *(u16x8*)(sB[buf] + bb) = rb0;
    *(u16x8*)(sB[buf] + (bb ^ 16)) = rb1;
    *(u16x8*)(sB[buf] + (bb ^ 32)) = rb2;
    *(u16x8*)(sB[buf] + (bb ^ 48)) = rb3;
  };

  stage_load(0);
  stage_write(0);
  __syncthreads();
  int cur = 0;
  for (int it = 0; it < 8; ++it) {
    if (it < 7) stage_load((it + 1) * 32);
    int ra = wid * 16 + l15;
    bf16x8 af = *(const bf16x8*)(sA[cur] + ((ra << 6) + (l4 << 4) ^ ((ra & 7) << 4)));
    #pragma unroll
    for (int n4 = 0; n4 < 16; ++n4) {
      int rn = n4 * 16 + l15;
      bf16x8 bf = *(const bf16x8*)(sB[cur] + ((rn << 6) + (l4 << 4) ^ ((rn & 7) << 4)));
      acc[n4] = __builtin_amdgcn_mfma_f32_16x16x32_bf16(af, bf, acc[n4], 0, 0, 0);
    }
    __syncthreads();
    if (it < 7) {
      stage_write(cur ^ 1);
      __syncthreads();
      cur ^= 1;
    }
  }
  const int row = bm + wid * 16 + l4 * 4;
  const float* rs = g.rs[j];
  const float* c0 = g.c0[j];
  const float* cvec = g.cvec[j];
  unsigned short* Cout = g.out[j];
  float rsv[4];
  if (rs) {
    #pragma unroll
    for (int jj = 0; jj < 4; ++jj) rsv[jj] = rs[row + jj];
  }
  #pragma unroll
  for (int n4 = 0; n4 < 16; ++n4) {
    int col = n4 * 16 + l15;
    float base = c0 ? c0[col] : 0.0f;
    float cv = rs ? cvec[col] : 0.0f;
    #pragma unroll
    for (int jj = 0; jj < 4; ++jj) {
      float v = acc[n4][jj] + base;
      if (rs) v += rsv[jj] * cv;
      Cout[(size_t)(row + jj) * 256 + col] = f2bf(v);
    }
  }
}

// batched out-projection GEMM (2 jobs, fp32 strided out into taa halves)
__global__ __launch_bounds__(256) void gemmout2_kernel(
    const unsigned short* __restrict__ A0, const unsigned short* __restrict__ W0,
    const float* __restrict__ b0,
    const unsigned short* __restrict__ A1, const unsigned short* __restrict__ W1,
    const float* __restrict__ b1,
    float* __restrict__ Cout)
{
  const int job = blockIdx.x >= (NN / 64);
  const int bm = (blockIdx.x - (job ? NN / 64 : 0)) * 64;
  const unsigned short* Ain = job ? A1 : A0;
  const unsigned short* Wt  = job ? W1 : W0;
  const float* c0 = job ? b1 : b0;
  const int coff = job ? 0 : 256;

  __shared__ __align__(16) char sA[2][4096];
  __shared__ __align__(16) char sB[2][16384];
  const int tid = threadIdx.x, lane = tid & 63, wid = tid >> 6;
  const int l15 = lane & 15, l4 = lane >> 4;

  f32x4 acc[16] = {};
  const int ar = tid >> 2, akq = (tid & 3) * 8;
  const int bn = tid;
  u16x8 ua, rb0, rb1, rb2, rb3;
  auto stage_load = [&](int k0) {
    ua = *(const u16x8*)(Ain + (size_t)(bm + ar) * 256 + k0 + akq);
    const unsigned short* bp = Wt + (size_t)bn * 256 + k0;
    rb0 = *(const u16x8*)bp;        rb1 = *(const u16x8*)(bp + 8);
    rb2 = *(const u16x8*)(bp + 16); rb3 = *(const u16x8*)(bp + 24);
  };
  auto stage_write = [&](int buf) {
    int aa = ((ar << 6) + (akq << 1)) ^ ((ar & 7) << 4);
    *(u16x8*)(sA[buf] + aa) = ua;
    int bb = (bn << 6) ^ ((bn & 7) << 4);
    *(u16x8*)(sB[buf] + bb) = rb0;
    *(u16x8*)(sB[buf] + (bb ^ 16)) = rb1;
    *(u16x8*)(sB[buf] + (bb ^ 32)) = rb2;
    *(u16x8*)(sB[buf] + (bb ^ 48)) = rb3;
  };
  stage_load(0);
  stage_write(0);
  __syncthreads();
  int cur = 0;
  for (int it = 0; it < 8; ++it) {
    if (it < 7) stage_load((it + 1) * 32);
    int ra = wid * 16 + l15;
    bf16x8 af = *(const bf16x8*)(sA[cur] + ((ra << 6) + (l4 << 4) ^ ((ra & 7) << 4)));
    #pragma unroll
    for (int n4 = 0; n4 < 16; ++n4) {
      int rn = n4 * 16 + l15;
      bf16x8 bf = *(const bf16x8*)(sB[cur] + ((rn << 6) + (l4 << 4) ^ ((rn & 7) << 4)));
      acc[n4] = __builtin_amdgcn_mfma_f32_16x16x32_bf16(af, bf, acc[n4], 0, 0, 0);
    }
    __syncthreads();
    if (it < 7) {
      stage_write(cur ^ 1);
      __syncthreads();
      cur ^= 1;
    }
  }
  const int row = bm + wid * 16 + l4 * 4;
  #pragma unroll
  for (int n4 = 0; n4 < 16; ++n4) {
    int col = n4 * 16 + l15;
    float base = c0[col];
    #pragma unroll
    for (int jj = 0; jj < 4; ++jj)
      Cout[(size_t)(row + jj) * 512 + coff + col] = acc[n4][jj] + base;
  }
}

// ================= batched CSR build =================
struct CooPtrs {
  const int* rw[6];
  const int* cl[6];
  const float* vl[6];
};
static __device__ __forceinline__ void coo_block_resolve(
    int b, int& g, int& eb, int& rb)
{
  if      (b < 1920) { g = 0; eb = 0;    rb = 0; }
  else if (b < 3840) { g = 1; eb = 1920; rb = NN; }
  else if (b < 6080) { g = 2; eb = 3840; rb = 2 * NN; }
  else if (b < 8000) { g = 3; eb = 6080; rb = 2 * NN + MM; }
  else if (b < 9920) { g = 4; eb = 8000; rb = 3 * NN + MM; }
  else               { g = 5; eb = 9920; rb = 4 * NN + MM; }
}

__global__ __launch_bounds__(256) void count_all_kernel(
    CooPtrs coo, int* __restrict__ cnt)
{
  int g, eb, rb;
  coo_block_resolve(blockIdx.x, g, eb, rb);
  int e = (blockIdx.x - eb) * 256 + threadIdx.x;
  atomicAdd(&cnt[rb + coo.rw[g][e]], 1);
}

__global__ __launch_bounds__(256) void scan1_kernel(
    const int* __restrict__ cnt, int* __restrict__ bsum, int n)
{
  __shared__ int sh[256];
  int i = blockIdx.x * 256 + threadIdx.x;
  sh[threadIdx.x] = (i < n) ? cnt[i] : 0;
  __syncthreads();
  for (int off = 128; off; off >>= 1) {
    if (threadIdx.x < off) sh[threadIdx.x] += sh[threadIdx.x + off];
    __syncthreads();
  }
  if (threadIdx.x == 0) bsum[blockIdx.x] = sh[0];
}

__global__ __launch_bounds__(256) void scan2_kernel(int* __restrict__ bsum, int nb)
{
  __shared__ int sh[256];
  int t = threadIdx.x;
  int carry = 0;
  for (int base = 0; base < nb; base += 256) {
    int i = base + t;
    int v = (i < nb) ? bsum[i] : 0;
    sh[t] = v;
    __syncthreads();
    for (int off = 1; off < 256; off <<= 1) {
      int add = (t >= off) ? sh[t - off] : 0;
      __syncthreads();
      sh[t] += add;
      __syncthreads();
    }
    int incl = sh[t];
    int tot = sh[255];
    if (i < nb) bsum[i] = carry + incl - v;
    carry += tot;
    __syncthreads();
  }
}

__global__ __launch_bounds__(256) void scan3_kernel(
    const int* __restrict__ cnt, const int* __restrict__ bsum,
    int* __restrict__ rowptr, int* __restrict__ cntz, int n)
{
  __shared__ int sh[256];
  int i = blockIdx.x * 256 + threadIdx.x;
  int v = (i < n) ? cnt[i] : 0;
  sh[threadIdx.x] = v;
  __syncthreads();
  for (int off = 1; off < 256; off <<= 1) {
    int add = (threadIdx.x >= off) ? sh[threadIdx.x - off] : 0;
    __syncthreads();
    sh[threadIdx.x] += add;
    __syncthreads();
  }
  int incl = sh[threadIdx.x];
  int base = bsum[blockIdx.x];
  if (i < n) { rowptr[i] = base + incl - v; cntz[i] = 0; }
  if (i == n - 1) rowptr[n] = base + incl;
}

__global__ __launch_bounds__(256) void fill_all_kernel(
    CooPtrs coo, const int* __restrict__ P, int* __restrict__ cur,
    int2* __restrict__ epack)
{
  int g, eb, rb;
  coo_block_resolve(blockIdx.x, g, eb, rb);
  int e = (blockIdx.x - eb) * 256 + threadIdx.x;
  int grow = rb + coo.rw[g][e];
  int pos = P[grow] + atomicAdd(&cur[grow], 1);
  epack[pos] = make_int2(coo.cl[g][e], __float_as_int(coo.vl[g][e]));
}

__global__ __launch_bounds__(256) void rowsum_all_kernel(
    const int* __restrict__ P, const int2* __restrict__ epack,
    float* __restrict__ rsAll)
{
  int j = blockIdx.x * 256 + threadIdx.x;
  int g = j / NN;
  int r = j - g * NN;
  int grow = (g == 0 ? 2 * NN + MM : g == 1 ? 3 * NN + MM : 4 * NN + MM) + r;
  float s = 0.0f;
  int end = P[grow + 1];
  for (int e = P[grow]; e < end; ++e) s += __int_as_float(epack[e].y);
  rsAll[j] = s;
}

// ---------------- batched CSR SpMM (3 jobs), wave-per-row -------------------
struct Spmm3 {
  const int* rowptr[3];
  const unsigned short* X[3];
  unsigned short* Y[3];
  float* Y2[3];
  const float* bias[3];
  int src_rows[3];
  int bs1, bs2;
};
__global__ __launch_bounds__(256) void spmm3_kernel(
    Spmm3 s, const int2* __restrict__ ep, int relu)
{
  const int b = blockIdx.x;
  const int j = (b >= s.bs2) ? 2 : (b >= s.bs1 ? 1 : 0);
  const int rblk = b - (j == 2 ? s.bs2 : j == 1 ? s.bs1 : 0);
  const int wave = threadIdx.x >> 6, lane = threadIdx.x & 63;
  const int r = rblk * 4 + wave;
  const int f0 = lane * 4;
  const int src_rows = s.src_rows[j];
  const unsigned short* X = s.X[j];
  const int* rowptr = s.rowptr[j];
  int e = rowptr[r], end = rowptr[r + 1];
  float a0 = 0.0f, a1 = 0.0f, a2 = 0.0f, a3 = 0.0f;
  for (; e + 3 < end; e += 4) {
    int2 cv0 = ep[e], cv1 = ep[e + 1], cv2 = ep[e + 2], cv3 = ep[e + 3];
    ushort4 x0 = {0,0,0,0}, x1 = {0,0,0,0}, x2 = {0,0,0,0}, x3 = {0,0,0,0};
    if (cv0.x < src_rows) x0 = *(const ushort4*)(X + (size_t)cv0.x * DD + f0);
    if (cv1.x < src_rows) x1 = *(const ushort4*)(X + (size_t)cv1.x * DD + f0);
    if (cv2.x < src_rows) x2 = *(const ushort4*)(X + (size_t)cv2.x * DD + f0);
    if (cv3.x < src_rows) x3 = *(const ushort4*)(X + (size_t)cv3.x * DD + f0);
    float v0 = __int_as_float(cv0.y), v1 = __int_as_float(cv1.y);
    float v2 = __int_as_float(cv2.y), v3 = __int_as_float(cv3.y);
    if (cv0.x < src_rows) { a0 += v0*bf2f(x0.x); a1 += v0*bf2f(x0.y); a2 += v0*bf2f(x0.z); a3 += v0*bf2f(x0.w); }
    if (cv1.x < src_rows) { a0 += v1*bf2f(x1.x); a1 += v1*bf2f(x1.y); a2 += v1*bf2f(x1.z); a3 += v1*bf2f(x1.w); }
    if (cv2.x < src_rows) { a0 += v2*bf2f(x2.x); a1 += v2*bf2f(x2.y); a2 += v2*bf2f(x2.z); a3 += v2*bf2f(x2.w); }
    if (cv3.x < src_rows) { a0 += v3*bf2f(x3.x); a1 += v3*bf2f(x3.y); a2 += v3*bf2f(x3.z); a3 += v3*bf2f(x3.w); }
  }
  for (; e < end; ++e) {
    int2 cv = ep[e];
    if (cv.x < src_rows) {
      float v = __int_as_float(cv.y);
      ushort4 xx = *(const ushort4*)(X + (size_t)cv.x * DD + f0);
      a0 += v * bf2f(xx.x); a1 += v * bf2f(xx.y);
      a2 += v * bf2f(xx.z); a3 += v * bf2f(xx.w);
    }
  }
  const float* bias = s.bias[j];
  if (bias) {
    a0 += bias[f0]; a1 += bias[f0 + 1]; a2 += bias[f0 + 2]; a3 += bias[f0 + 3];
  }
  if (relu) {
    a0 = fmaxf(a0, 0.0f); a1 = fmaxf(a1, 0.0f);
    a2 = fmaxf(a2, 0.0f); a3 = fmaxf(a3, 0.0f);
  }
  uint2 yb = { cvtpk(a0, a1), cvtpk(a2, a3) };
  *(uint2*)(s.Y[j] + (size_t)r * DD + f0) = yb;
  if (s.Y2[j]) {
    float4 yf = {a0, a1, a2, a3};
    *(float4*)(s.Y2[j] + (size_t)r * DD + f0) = yf;
  }
}

// ---------------- MFMA flash attention: BOTH MHAs in one dispatch ----------
// grid 12288 = 2 x (48 chunks x 8 heads x 16 qblocks); XCD-swizzled.
// P-LDS swizzle at 32B granule: ^((q&3)<<5) — conflict-free write AND read.
__global__ __launch_bounds__(256) void attn2_kernel(
    const unsigned short* __restrict__ Q1, const unsigned short* __restrict__ K1,
    const unsigned short* __restrict__ V1, unsigned short* __restrict__ O1,
    const unsigned short* __restrict__ Q2, const unsigned short* __restrict__ K2,
    const unsigned short* __restrict__ V2, unsigned short* __restrict__ O2)
{
  __shared__ __align__(16) char sKb[4096];
  __shared__ __align__(16) char sVb[4096];
  __shared__ __align__(16) char sPb[8192];
  const int wgid = (blockIdx.x & 7) * 1536 + (blockIdx.x >> 3);
  const int qb = wgid & 15, h = (wgid >> 4) & 7, cc = wgid >> 7;   // cc 0..95
  const int job = cc >= 48;
  const int c = cc - (job ? 48 : 0);
  const unsigned short* Q = job ? Q2 : Q1;
  const unsigned short* K = job ? K2 : K1;
  const unsigned short* V = job ? V2 : V1;
  unsigned short* O = job ? O2 : O1;

  const int tid = threadIdx.x, lane = tid & 63, wid = tid >> 6;
  const int l15 = lane & 15, l4 = lane >> 4;
  char* sPw = sPb + wid * 2048;
  const size_t base = (size_t)c * (CHK * DD) + (size_t)h * DHEAD;
  const int q0 = qb * 64 + wid * 16;

  bf16x8 qf = *(const bf16x8*)(Q + base + (size_t)(q0 + l15) * DD + l4 * 8);

  const int key_s = tid >> 2, dq = (tid & 3) * 8;
  const unsigned short* Kp = K + base + (size_t)key_s * DD + dq;
  const unsigned short* Vp = V + base + (size_t)key_s * DD + dq;
  const int kaddr = ((key_s << 6) + (dq << 1)) ^ ((key_s & 7) << 4);

  f32x4 oacc[2] = {};
  float m = -1e30f, l = 0.0f;
  const f32x4 zero = {};

  for (int kt = 0; kt < CHK; kt += 64) {
    __syncthreads();
    u16x8 kv = *(const u16x8*)Kp;  Kp += 64 * DD;
    u16x8 vv = *(const u16x8*)Vp;  Vp += 64 * DD;
    *(u16x8*)(sKb + kaddr) = kv;
    #pragma unroll
    for (int i = 0; i < 8; ++i) {
      int d = dq + i;
      int bb = ((d << 7) + (key_s << 1))
             ^ ((d & 7) << 4) ^ (((d >> 3) & 3) << 5);
      *(unsigned short*)(sVb + bb) = vv[i];
    }
    __syncthreads();

    f32x4 s[4];
    #pragma unroll
    for (int s4 = 0; s4 < 4; ++s4) {
      int key = s4 * 16 + l15;
      int ba = ((key << 6) + (l4 << 4)) ^ ((key & 7) << 4);
      bf16x8 kf = *(const bf16x8*)(sKb + ba);
      s[s4] = __builtin_amdgcn_mfma_f32_16x16x32_bf16(kf, qf, zero, 0, 0, 0);
    }
    // tmax via max3 tree (exact; clang fuses to v_max3_f32)
    float t0 = max3f(s[0][0], s[0][1], s[0][2]);
    float t1 = max3f(s[0][3], s[1][0], s[1][1]);
    float t2 = max3f(s[1][2], s[1][3], s[2][0]);
    float t3 = max3f(s[2][1], s[2][2], s[2][3]);
    float t4 = max3f(s[3][0], s[3][1], s[3][2]);
    float tmax = max3f(max3f(t0, t1, t2), fmaxf(t3, t4), s[3][3]);
    tmax = fmaxf(tmax, __shfl_xor(tmax, 16));
    tmax = fmaxf(tmax, __shfl_xor(tmax, 32));
    bool skip = __all(tmax - m <= 8.0f);
    float mnew = skip ? m : fmaxf(m, tmax);
    if (!skip) {
      float corr = __builtin_amdgcn_exp2f(m - mnew);
      l *= corr;
      oacc[0] *= corr;
      oacc[1] *= corr;
    }
    float psum = 0.0f;
    float p[4][4];
    #pragma unroll
    for (int s4 = 0; s4 < 4; ++s4)
      #pragma unroll
      for (int j = 0; j < 4; ++j) {
        p[s4][j] = __builtin_amdgcn_exp2f(s[s4][j] - mnew);
        psum += p[s4][j];
      }
    psum += __shfl_xor(psum, 16);
    psum += __shfl_xor(psum, 32);
    l += psum;
    m = mnew;
    // P write: 32B-granule swizzle ^((l15&3)<<5); l4*8 span fits granule
    #pragma unroll
    for (int s4 = 0; s4 < 4; ++s4) {
      uint2 pk = { cvtpk(p[s4][0], p[s4][1]), cvtpk(p[s4][2], p[s4][3]) };
      int bp = ((l15 << 7) + (s4 << 5) + (l4 << 3)) ^ ((l15 & 3) << 5);
      *(uint2*)(sPw + bp) = pk;
    }
    __syncthreads();

    #pragma unroll
    for (int dh = 0; dh < 2; ++dh)
      #pragma unroll
      for (int kh = 0; kh < 2; ++kh) {
        int d = dh * 16 + l15;
        int ba = ((d << 7) + ((kh * 32 + l4 * 8) << 1))
               ^ ((d & 7) << 4) ^ (((d >> 3) & 3) << 5);
        bf16x8 vf = *(const bf16x8*)(sVb + ba);
        int bp = ((l15 << 7) + (kh << 6) + (l4 << 4)) ^ ((l15 & 3) << 5);
        bf16x8 pf = *(const bf16x8*)(sPw + bp);
        oacc[dh] = __builtin_amdgcn_mfma_f32_16x16x32_bf16(vf, pf, oacc[dh], 0, 0, 0);
      }
  }

  float inv = 1.0f / l;
  unsigned short* orow = O + base + (size_t)(q0 + l15) * DD;
  #pragma unroll
  for (int dh = 0; dh < 2; ++dh) {
    uint2 o2 = { cvtpk(oacc[dh][0] * inv, oacc[dh][1] * inv),
                 cvtpk(oacc[dh][2] * inv, oacc[dh][3] * inv) };
    *(uint2*)(orow + dh * 16 + l4 * 4) = o2;
  }
}

__global__ __launch_bounds__(256) void fill_kernel(float* p, long n, float v)
{
  long i = (long)blockIdx.x * 256 + threadIdx.x;
  if (i < n) p[i] = v;
}

extern "C" void kernel_launch(void* const* d_in, const int* in_sizes, int n_in,
                              void* d_out, int out_size, void* d_ws, size_t ws_size,
                              hipStream_t stream)
{
  const float* x     = (const float*)d_in[0];
  const int*   Acg_r = (const int*)d_in[1];
  const int*   Acg_c = (const int*)d_in[2];
  const float* Acg_v = (const float*)d_in[3];
  const int*   Ahy_r = (const int*)d_in[4];
  const int*   Ahy_c = (const int*)d_in[5];
  const float* Ahy_v = (const float*)d_in[6];
  const int*   Asg_r = (const int*)d_in[7];
  const int*   Asg_c = (const int*)d_in[8];
  const float* Asg_v = (const float*)d_in[9];
  const int*   Lcg_r = (const int*)d_in[10];
  const int*   Lcg_c = (const int*)d_in[11];
  const float* Lcg_v = (const float*)d_in[12];
  const int*   Lhy_r = (const int*)d_in[13];
  const int*   Lhy_c = (const int*)d_in[14];
  const float* Lhy_v = (const float*)d_in[15];
  const int*   Lsg_r = (const int*)d_in[16];
  const int*   Lsg_c = (const int*)d_in[17];
  const float* Lsg_v = (const float*)d_in[18];
  const float* cg_W  = (const float*)d_in[19];
  const float* cg_b  = (const float*)d_in[20];
  const float* hg_W  = (const float*)d_in[21];
  const float* hg_b  = (const float*)d_in[22];
  const float* sg_W  = (const float*)d_in[23];
  const float* sg_b  = (const float*)d_in[24];
  const float* snh_W = (const float*)d_in[25];
  const float* snh_b = (const float*)d_in[26];
  const float* snc_W = (const float*)d_in[27];
  const float* snc_b = (const float*)d_in[28];
  const float* sns_W = (const float*)d_in[29];
  const float* sns_b = (const float*)d_in[30];
  const float* spa_hyp_W  = (const float*)d_in[31];
  const float* spa_hyp_b  = (const float*)d_in[32];
  const float* spa_star_W = (const float*)d_in[33];
  const float* spa_star_b = (const float*)d_in[34];
  const float* spa_clq_W  = (const float*)d_in[35];
  const float* spa_clq_b  = (const float*)d_in[36];
  const float* spa_in_w   = (const float*)d_in[37];
  const float* spa_in_b   = (const float*)d_in[38];
  const float* spa_out_w  = (const float*)d_in[39];
  const float* spa_out_b  = (const float*)d_in[40];
  const float* spe_hyp_W  = (const float*)d_in[41];
  const float* spe_hyp_b  = (const float*)d_in[42];
  const float* spe_star_W = (const float*)d_in[43];
  const float* spe_star_b = (const float*)d_in[44];
  const float* spe_clq_W  = (const float*)d_in[45];
  const float* spe_clq_b  = (const float*)d_in[46];
  const float* spe_in_w   = (const float*)d_in[47];
  const float* spe_in_b   = (const float*)d_in[48];
  const float* spe_out_w  = (const float*)d_in[49];
  const float* spe_out_b  = (const float*)d_in[50];

  float* out = (float*)d_out;

  const size_t NF = (size_t)NN * DD;
  const size_t MF = (size_t)MM * DD;
  const size_t WELEMS  = 14u * 65536u;
  const size_t need = (14 * NF + 3 * MF) * 2
                    + (size_t)ETOT * 8
                    + ((size_t)3 * NN + 65536 + 256 + 4096) * 4
                    + ((size_t)ROWS_TOT + 1 + ROWS_TOT + 2048) * 4
                    + WELEMS * 2;

  auto fill = [&](float v) {
    long tot = (long)out_size;
    fill_kernel<<<dim3((unsigned)((tot + 255) / 256)), 256, 0, stream>>>(out, tot, v);
  };
  if (ws_size < need)                        { fill(12.0f); return; }
  if (n_in != 51)                            { fill(16.0f); return; }
  if (in_sizes[0] != NN * FD)                { fill(20.0f); return; }
  if (in_sizes[3] != NEN)                    { fill(24.0f); return; }
  if (in_sizes[9] != NEM)                    { fill(28.0f); return; }
  if (in_sizes[19] != 2 * FD * DD)           { fill(32.0f); return; }
  if (in_sizes[37] != 3 * DD * DD)           { fill(36.0f); return; }
  if (out_size != NN * 512 + NN * DD + EHN * DD) { fill(40.0f); return; }

  // ---- bf16 buffers ----
  unsigned short* Tcg = (unsigned short*)d_ws;
  unsigned short* Thy = Tcg + NF;
  unsigned short* Tsg = Thy + NF;
  unsigned short* Hcg = Tsg + NF;
  unsigned short* Hhy = Hcg + NF;
  unsigned short* Hsg = Hhy + NF;                // M
  unsigned short* Usg = Hsg + MF;                // M
  unsigned short* SG  = Usg + MF;                // M
  unsigned short* CG  = SG + MF;
  unsigned short* HG  = CG + NF;
  unsigned short* LH  = HG + NF;
  unsigned short* LC  = LH + NF;
  unsigned short* LS  = LC + NF;
  unsigned short* QH  = LS + NF;
  unsigned short* KH  = QH + NF;
  unsigned short* VH  = KH + NF;
  unsigned short* AOx = VH + NF;                 // kept for layout stability
  unsigned short* Ucg = Tcg;    // alias (T dead before layer-2 writes U)
  unsigned short* Uhy = Thy;
  unsigned short* Q2  = LH;     // alias: spatial QKV after LH/LC/LS consumed
  unsigned short* K2  = LC;
  unsigned short* V2  = LS;
  unsigned short* AO1 = Hcg;    // alias: H dead after layer-2 GEMM
  unsigned short* AO2 = Hhy;
  (void)AOx;

  int2* epack = (int2*)(AOx + NF);
  float* fp = (float*)(epack + ETOT);
  float* rsAll = fp;           fp += 3 * NN;
  float* tmp256 = fp;          fp += 65536;
  float* tmpv = fp;            fp += 256;
  float* CB = fp;              fp += 4096;
  int* P    = (int*)fp;
  int* cnt  = P + ROWS_TOT + 1;
  int* bsum = cnt + ROWS_TOT;
  unsigned short* WB = (unsigned short*)(bsum + 2048);

  int* rp_cg  = P;
  int* rp_hy  = P + NN;
  int* rp_sg  = P + 2 * NN;
  int* rp_Lcg = P + 2 * NN + MM;
  int* rp_Lhy = P + 3 * NN + MM;
  int* rp_Lsg = P + 4 * NN + MM;
  float* rs_c = rsAll;
  float* rs_h = rsAll + NN;
  float* rs_s = rsAll + 2 * NN;

  auto wslot = [&](int s) { return WB + (size_t)s * 65536; };
  auto cb    = [&](int s) { return CB + (size_t)s * 256; };

  auto combine = [&](const float* Bw, const float* Aw, const float* ab,
                     const float* bb, unsigned short* Wc, float* bcp, float fs) {
    combine_w_kernel<<<dim3(256), 256, 0, stream>>>(Bw, Aw, ab, bb, Wc, bcp, fs);
  };
  auto combine3 = [&](const float* w3, const float* b3, const float* pW,
                      const float* pb, const float* sW, const float* sb,
                      unsigned short* Wc, float* cvecp, float* c0p, float fs) {
    mm256f_kernel<<<dim3(256), 256, 0, stream>>>(pW, sW, tmp256);
    mm256b_kernel<<<dim3(256), 256, 0, stream>>>(w3, tmp256, Wc, fs);
    mv256_kernel<<<dim3(1), 256, 0, stream>>>(pW, sb, nullptr, tmpv, 1.0f);
    mv256_kernel<<<dim3(1), 256, 0, stream>>>(w3, tmpv, nullptr, cvecp, fs);
    mv256_kernel<<<dim3(1), 256, 0, stream>>>(w3, pb, b3, c0p, fs);
  };

  const float fsQ = 0.17677669529663687f * 1.4426950408889634f;

  // ================= weight prep =================
  {
    CastJobs jobs;
    jobs.src[0] = cg_W;           jobs.dst[0] = wslot(0);  jobs.trans[0] = 1;
    jobs.src[1] = cg_W + FD * DD; jobs.dst[1] = wslot(1);  jobs.trans[1] = 1;
    jobs.src[2] = hg_W;           jobs.dst[2] = wslot(2);  jobs.trans[2] = 1;
    jobs.src[3] = hg_W + FD * DD; jobs.dst[3] = wslot(3);  jobs.trans[3] = 1;
    jobs.src[4] = sg_W;           jobs.dst[4] = wslot(4);  jobs.trans[4] = 1;
    jobs.src[5] = sg_W + FD * DD; jobs.dst[5] = wslot(5);  jobs.trans[5] = 1;
    jobs.src[6] = spa_out_w;      jobs.dst[6] = wslot(12); jobs.trans[6] = 0;
    jobs.src[7] = spe_out_w;      jobs.dst[7] = wslot(13); jobs.trans[7] = 0;
    cast_w8_kernel<<<dim3(8 * 256), 256, 0, stream>>>(jobs);
  }
  combine(spa_in_w,                spa_hyp_W,  spa_hyp_b,  spa_in_b,          wslot(6), cb(0), fsQ);
  combine(spa_in_w + DD * DD,      spa_star_W, spa_star_b, spa_in_b + DD,     wslot(7), cb(1), 1.0f);
  combine(spa_in_w + 2 * DD * DD,  spa_clq_W,  spa_clq_b,  spa_in_b + 2 * DD, wslot(8), cb(2), 1.0f);
  combine3(spe_in_w,               spe_in_b,            spe_hyp_W,  spe_hyp_b,  snh_W, snh_b, wslot(9),  cb(3), cb(4), fsQ);
  combine3(spe_in_w + DD * DD,     spe_in_b + DD,       spe_star_W, spe_star_b, snc_W, snc_b, wslot(10), cb(5), cb(6), 1.0f);
  combine3(spe_in_w + 2 * DD * DD, spe_in_b + 2 * DD,   spe_clq_W,  spe_clq_b,  sns_W, sns_b, wslot(11), cb(7), cb(8), 1.0f);

  // ================= batched CSR build =================
  {
    CooPtrs coo;
    coo.rw[0] = Acg_r; coo.cl[0] = Acg_c; coo.vl[0] = Acg_v;
    coo.rw[1] = Ahy_r; coo.cl[1] = Ahy_c; coo.vl[1] = Ahy_v;
    coo.rw[2] = Asg_r; coo.cl[2] = Asg_c; coo.vl[2] = Asg_v;
    coo.rw[3] = Lcg_r; coo.cl[3] = Lcg_c; coo.vl[3] = Lcg_v;
    coo.rw[4] = Lhy_r; coo.cl[4] = Lhy_c; coo.vl[4] = Lhy_v;
    coo.rw[5] = Lsg_r; coo.cl[5] = Lsg_c; coo.vl[5] = Lsg_v;
    hipMemsetAsync(cnt, 0, (size_t)ROWS_TOT * 4, stream);
    count_all_kernel<<<dim3(ETOT / 256), 256, 0, stream>>>(coo, cnt);
    scan1_kernel<<<dim3(ROWS_TOT / 256), 256, 0, stream>>>(cnt, bsum, ROWS_TOT);
    scan2_kernel<<<dim3(1), 256, 0, stream>>>(bsum, ROWS_TOT / 256);
    scan3_kernel<<<dim3(ROWS_TOT / 256), 256, 0, stream>>>(cnt, bsum, P, cnt, ROWS_TOT);
    fill_all_kernel<<<dim3(ETOT / 256), 256, 0, stream>>>(coo, P, cnt, epack);
    rowsum_all_kernel<<<dim3(3 * NN / 256), 256, 0, stream>>>(P, epack, rsAll);
  }

  // ================= expansion nets (batched x3) =================
  {
    Gemm3 g = {};
    for (int j = 0; j < 3; ++j) { g.A[j] = x; g.c0[j] = nullptr; g.rs[j] = nullptr; }
    g.W[0] = wslot(0); g.out[0] = Tcg;
    g.W[1] = wslot(2); g.out[1] = Thy;
    g.W[2] = wslot(4); g.out[2] = Tsg;
    g.bs1 = 768; g.bs2 = 1536; g.btot = 2304;
    gemm3_kernel<0><<<dim3(2304), 256, 0, stream>>>(g);
  }
  {
    Spmm3 s = {};
    s.rowptr[0] = rp_cg; s.X[0] = Tcg; s.Y[0] = Hcg; s.Y2[0] = nullptr; s.bias[0] = cg_b; s.src_rows[0] = NN;
    s.rowptr[1] = rp_hy; s.X[1] = Thy; s.Y[1] = Hhy; s.Y2[1] = nullptr; s.bias[1] = hg_b; s.src_rows[1] = NN;
    s.rowptr[2] = rp_sg; s.X[2] = Tsg; s.Y[2] = Hsg; s.Y2[2] = nullptr; s.bias[2] = sg_b; s.src_rows[2] = NN;
    s.bs1 = NN / 4; s.bs2 = 2 * (NN / 4);
    spmm3_kernel<<<dim3(2 * (NN / 4) + MM / 4), 256, 0, stream>>>(s, epack, 1);
  }
  {
    Gemm3 g = {};
    g.A[0] = Hcg; g.W[0] = wslot(1); g.out[0] = Ucg;
    g.A[1] = Hhy; g.W[1] = wslot(3); g.out[1] = Uhy;
    g.A[2] = Hsg; g.W[2] = wslot(5); g.out[2] = Usg;
    for (int j = 0; j < 3; ++j) { g.c0[j] = nullptr; g.rs[j] = nullptr; }
    g.bs1 = NN / 64; g.bs2 = 2 * (NN / 64); g.btot = 2 * (NN / 64) + MM / 64;
    gemm3_kernel<1><<<dim3(2 * (NN / 64) + MM / 64), 256, 0, stream>>>(g);
  }
  {
    Spmm3 s = {};
    s.rowptr[0] = rp_cg; s.X[0] = Ucg; s.Y[0] = CG; s.Y2[0] = nullptr; s.bias[0] = cg_b + DD; s.src_rows[0] = NN;
    s.rowptr[1] = rp_hy; s.X[1] = Uhy; s.Y[1] = HG; s.Y2[1] = nullptr; s.bias[1] = hg_b + DD; s.src_rows[1] = NN;
    s.rowptr[2] = rp_sg; s.X[2] = Usg; s.Y[2] = SG; s.Y2[2] = out + (size_t)NN * 512; s.bias[2] = sg_b + DD; s.src_rows[2] = MM;
    s.bs1 = NN / 4; s.bs2 = 2 * (NN / 4);
    spmm3_kernel<<<dim3(2 * (NN / 4) + MM / 4), 256, 0, stream>>>(s, epack, 0);
  }
  {
    Spmm3 s = {};
    s.rowptr[0] = rp_Lhy; s.X[0] = HG; s.Y[0] = LH; s.Y2[0] = nullptr; s.bias[0] = nullptr; s.src_rows[0] = NN;
    s.rowptr[1] = rp_Lcg; s.X[1] = CG; s.Y[1] = LC; s.Y2[1] = nullptr; s.bias[1] = nullptr; s.src_rows[1] = NN;
    s.rowptr[2] = rp_Lsg; s.X[2] = SG; s.Y[2] = LS; s.Y2[2] = nullptr; s.bias[2] = nullptr; s.src_rows[2] = MM;
    s.bs1 = NN / 4; s.bs2 = 2 * (NN / 4);
    spmm3_kernel<<<dim3(3 * (NN / 4)), 256, 0, stream>>>(s, epack, 0);
  }

  // ================= both MHAs =================
  {  // spectral QKV: LH/LC/LS -> QH/KH/VH
    Gemm3 g = {};
    g.A[0] = LH; g.W[0] = wslot(9);  g.c0[0] = cb(4); g.rs[0] = rs_h; g.cvec[0] = cb(3); g.out[0] = QH;
    g.A[1] = LC; g.W[1] = wslot(10); g.c0[1] = cb(6); g.rs[1] = rs_c; g.cvec[1] = cb(5); g.out[1] = KH;
    g.A[2] = LS; g.W[2] = wslot(11); g.c0[2] = cb(8); g.rs[2] = rs_s; g.cvec[2] = cb(7); g.out[2] = VH;
    g.bs1 = 768; g.bs2 = 1536; g.btot = 2304;
    gemm3_kernel<1><<<dim3(2304), 256, 0, stream>>>(g);
  }
  {  // spatial QKV: HG/CG/SG -> Q2/K2/V2 (reuse dead LH/LC/LS)
    Gemm3 g = {};
    g.A[0] = HG; g.W[0] = wslot(6); g.c0[0] = cb(0); g.rs[0] = nullptr; g.out[0] = Q2;
    g.A[1] = CG; g.W[1] = wslot(7); g.c0[1] = cb(1); g.rs[1] = nullptr; g.out[1] = K2;
    g.A[2] = SG; g.W[2] = wslot(8); g.c0[2] = cb(2); g.rs[2] = nullptr; g.out[2] = V2;
    g.bs1 = 768; g.bs2 = 1536; g.btot = 2304;
    gemm3_kernel<1><<<dim3(2304), 256, 0, stream>>>(g);
  }
  attn2_kernel<<<dim3(12288), 256, 0, stream>>>(QH, KH, VH, AO1,
                                                Q2, K2, V2, AO2);
  gemmout2_kernel<<<dim3(2 * (NN / 64)), 256, 0, stream>>>(
      AO1, wslot(13), spe_out_b,       // job0: spectral -> taa cols 256..511
      AO2, wslot(12), spa_out_b,       // job1: spatial  -> taa cols 0..255
      out);
}

// Round 12
// 1594.361 us; speedup vs baseline: 1.0238x; 1.0238x over previous
//
#include <hip/hip_runtime.h>

// Problem dims (fixed by reference)
#define NN 49152
#define EHN 8192
#define MM (NN + EHN)       // 57344
#define FD 256
#define DD 256
#define NHEADS 8
#define DHEAD 32
#define CHK 1024
#define NEN (10 * NN)       // 491520
#define NEM (10 * MM)       // 573440
#define ROWS_TOT (4 * NN + 2 * MM)   // 311296
#define ETOT (4 * NEN + 2 * NEM)     // 3,112,960

typedef __bf16 bf16x8 __attribute__((ext_vector_type(8)));
typedef unsigned short u16x8 __attribute__((ext_vector_type(8)));
typedef float f32x4 __attribute__((ext_vector_type(4)));

static __device__ __forceinline__ unsigned short f2bf(float f) {
  unsigned int u = __float_as_uint(f);
  unsigned int r = (u + 0x7FFFu + ((u >> 16) & 1u)) >> 16;
  return (unsigned short)r;
}
static __device__ __forceinline__ float bf2f(unsigned short u) {
  return __uint_as_float((unsigned int)u << 16);
}
static __device__ __forceinline__ unsigned int cvtpk(float a, float b) {
  unsigned int r;
  asm("v_cvt_pk_bf16_f32 %0, %1, %2" : "=v"(r) : "v"(a), "v"(b));
  return r;
}
static __device__ __forceinline__ float max3f(float a, float b, float c) {
  return fmaxf(fmaxf(a, b), c);   // clang fuses to v_max3_f32
}

// ---------------- weight prep ----------------
struct CastJobs {
  const float* src[8];
  unsigned short* dst[8];
  int trans[8];
};
__global__ __launch_bounds__(256) void cast_w8_kernel(CastJobs jobs)
{
  int job = blockIdx.x >> 8;
  int i = (blockIdx.x & 255) * 256 + threadIdx.x;
  int n = i >> 8, k = i & 255;
  const float* src = jobs.src[job];
  float f = jobs.trans[job] ? src[(size_t)k * 256 + n] : src[i];
  jobs.dst[job][i] = f2bf(f);
}

__global__ __launch_bounds__(256) void combine_w_kernel(
    const float* __restrict__ Bw, const float* __restrict__ Aw,
    const float* __restrict__ ab, const float* __restrict__ bb,
    unsigned short* __restrict__ Wc, float* __restrict__ bc, float fscale)
{
  int n = blockIdx.x, t = threadIdx.x;
  __shared__ float shB[256];
  __shared__ float red[256];
  shB[t] = Bw[n * 256 + t];
  __syncthreads();
  float acc = 0.0f;
  #pragma unroll 8
  for (int j = 0; j < 256; ++j) acc += shB[j] * Aw[j * 256 + t];
  Wc[n * 256 + t] = f2bf(acc * fscale);
  red[t] = shB[t] * ab[t];
  __syncthreads();
  for (int off = 128; off; off >>= 1) {
    if (t < off) red[t] += red[t + off];
    __syncthreads();
  }
  if (t == 0) bc[n] = (red[0] + bb[n]) * fscale;
}

__global__ __launch_bounds__(256) void mm256f_kernel(
    const float* __restrict__ A, const float* __restrict__ B,
    float* __restrict__ C)
{
  int n = blockIdx.x, t = threadIdx.x;
  __shared__ float sa[256];
  sa[t] = A[n * 256 + t];
  __syncthreads();
  float acc = 0.0f;
  #pragma unroll 8
  for (int j = 0; j < 256; ++j) acc += sa[j] * B[j * 256 + t];
  C[n * 256 + t] = acc;
}

__global__ __launch_bounds__(256) void mm256b_kernel(
    const float* __restrict__ A, const float* __restrict__ B,
    unsigned short* __restrict__ W, float fs)
{
  int n = blockIdx.x, t = threadIdx.x;
  __shared__ float sa[256];
  sa[t] = A[n * 256 + t];
  __syncthreads();
  float acc = 0.0f;
  #pragma unroll 8
  for (int j = 0; j < 256; ++j) acc += sa[j] * B[j * 256 + t];
  W[n * 256 + t] = f2bf(acc * fs);
}

__global__ __launch_bounds__(256) void mv256_kernel(
    const float* __restrict__ W, const float* __restrict__ v,
    const float* __restrict__ add, float* __restrict__ outv, float fs)
{
  int t = threadIdx.x;
  __shared__ float sv[256];
  sv[t] = v[t];
  __syncthreads();
  float acc = 0.0f;
  #pragma unroll 8
  for (int k = 0; k < 256; ++k) acc += W[t * 256 + k] * sv[k];
  if (add) acc += add[t];
  outv[t] = fs * acc;
}

// ---------------- batched bf16-MFMA GEMM (3 jobs, bf16 out) ----------------
struct Gemm3 {
  const void* A[3];
  const unsigned short* W[3];
  const float* c0[3];
  const float* rs[3];
  const float* cvec[3];
  unsigned short* out[3];
  int bs1, bs2, btot;
};
template<int ABF>
__global__ __launch_bounds__(256) void gemm3_kernel(Gemm3 g)
{
  const int b = blockIdx.x;
  const int j = (b >= g.bs2) ? 2 : (b >= g.bs1 ? 1 : 0);
  const int bm = (b - (j == 2 ? g.bs2 : j == 1 ? g.bs1 : 0)) * 64;
  const void* Ain = g.A[j];
  const unsigned short* Wt = g.W[j];

  __shared__ __align__(16) char sA[2][4096];
  __shared__ __align__(16) char sB[2][16384];
  const int tid = threadIdx.x, lane = tid & 63, wid = tid >> 6;
  const int l15 = lane & 15, l4 = lane >> 4;

  f32x4 acc[16] = {};
  const int ar = tid >> 2, akq = (tid & 3) * 8;
  const int bn = tid;

  float4 fa0, fa1;
  u16x8 ua;
  u16x8 rb0, rb1, rb2, rb3;
  auto stage_load = [&](int k0) {
    if (ABF) {
      ua = *(const u16x8*)((const unsigned short*)Ain +
                           (size_t)(bm + ar) * 256 + k0 + akq);
    } else {
      const float* ap = (const float*)Ain + (size_t)(bm + ar) * 256 + k0 + akq;
      fa0 = *(const float4*)ap;
      fa1 = *(const float4*)(ap + 4);
    }
    const unsigned short* bp = Wt + (size_t)bn * 256 + k0;
    rb0 = *(const u16x8*)bp;        rb1 = *(const u16x8*)(bp + 8);
    rb2 = *(const u16x8*)(bp + 16); rb3 = *(const u16x8*)(bp + 24);
  };
  auto stage_write = [&](int buf) {
    u16x8 va;
    if (ABF) {
      va = ua;
    } else {
      va[0] = f2bf(fa0.x); va[1] = f2bf(fa0.y); va[2] = f2bf(fa0.z); va[3] = f2bf(fa0.w);
      va[4] = f2bf(fa1.x); va[5] = f2bf(fa1.y); va[6] = f2bf(fa1.z); va[7] = f2bf(fa1.w);
    }
    int aa = ((ar << 6) + (akq << 1)) ^ ((ar & 7) << 4);
    *(u16x8*)(sA[buf] + aa) = va;
    int bb = (bn << 6) ^ ((bn & 7) << 4);
    *(u16x8*)(sB[buf] + bb) = rb0;
    *(u16x8*)(sB[buf] + (bb ^ 16)) = rb1;
    *(u16x8*)(sB[buf] + (bb ^ 32)) = rb2;
    *(u16x8*)(sB[buf] + (bb ^ 48)) = rb3;
  };

  stage_load(0);
  stage_write(0);
  __syncthreads();
  int cur = 0;
  for (int it = 0; it < 8; ++it) {
    if (it < 7) stage_load((it + 1) * 32);
    int ra = wid * 16 + l15;
    bf16x8 af = *(const bf16x8*)(sA[cur] + ((ra << 6) + (l4 << 4) ^ ((ra & 7) << 4)));
    #pragma unroll
    for (int n4 = 0; n4 < 16; ++n4) {
      int rn = n4 * 16 + l15;
      bf16x8 bf = *(const bf16x8*)(sB[cur] + ((rn << 6) + (l4 << 4) ^ ((rn & 7) << 4)));
      acc[n4] = __builtin_amdgcn_mfma_f32_16x16x32_bf16(af, bf, acc[n4], 0, 0, 0);
    }
    __syncthreads();
    if (it < 7) {
      stage_write(cur ^ 1);
      __syncthreads();
      cur ^= 1;
    }
  }
  const int row = bm + wid * 16 + l4 * 4;
  const float* rs = g.rs[j];
  const float* c0 = g.c0[j];
  const float* cvec = g.cvec[j];
  unsigned short* Cout = g.out[j];
  float rsv[4];
  if (rs) {
    #pragma unroll
    for (int jj = 0; jj < 4; ++jj) rsv[jj] = rs[row + jj];
  }
  #pragma unroll
  for (int n4 = 0; n4 < 16; ++n4) {
    int col = n4 * 16 + l15;
    float base = c0 ? c0[col] : 0.0f;
    float cv = rs ? cvec[col] : 0.0f;
    #pragma unroll
    for (int jj = 0; jj < 4; ++jj) {
      float v = acc[n4][jj] + base;
      if (rs) v += rsv[jj] * cv;
      Cout[(size_t)(row + jj) * 256 + col] = f2bf(v);
    }
  }
}

// batched out-projection GEMM (2 jobs, fp32 strided out into taa halves)
__global__ __launch_bounds__(256) void gemmout2_kernel(
    const unsigned short* __restrict__ A0, const unsigned short* __restrict__ W0,
    const float* __restrict__ b0,
    const unsigned short* __restrict__ A1, const unsigned short* __restrict__ W1,
    const float* __restrict__ b1,
    float* __restrict__ Cout)
{
  const int job = blockIdx.x >= (NN / 64);
  const int bm = (blockIdx.x - (job ? NN / 64 : 0)) * 64;
  const unsigned short* Ain = job ? A1 : A0;
  const unsigned short* Wt  = job ? W1 : W0;
  const float* c0 = job ? b1 : b0;
  const int coff = job ? 0 : 256;

  __shared__ __align__(16) char sA[2][4096];
  __shared__ __align__(16) char sB[2][16384];
  const int tid = threadIdx.x, lane = tid & 63, wid = tid >> 6;
  const int l15 = lane & 15, l4 = lane >> 4;

  f32x4 acc[16] = {};
  const int ar = tid >> 2, akq = (tid & 3) * 8;
  const int bn = tid;
  u16x8 ua, rb0, rb1, rb2, rb3;
  auto stage_load = [&](int k0) {
    ua = *(const u16x8*)(Ain + (size_t)(bm + ar) * 256 + k0 + akq);
    const unsigned short* bp = Wt + (size_t)bn * 256 + k0;
    rb0 = *(const u16x8*)bp;        rb1 = *(const u16x8*)(bp + 8);
    rb2 = *(const u16x8*)(bp + 16); rb3 = *(const u16x8*)(bp + 24);
  };
  auto stage_write = [&](int buf) {
    int aa = ((ar << 6) + (akq << 1)) ^ ((ar & 7) << 4);
    *(u16x8*)(sA[buf] + aa) = ua;
    int bb = (bn << 6) ^ ((bn & 7) << 4);
    *(u16x8*)(sB[buf] + bb) = rb0;
    *(u16x8*)(sB[buf] + (bb ^ 16)) = rb1;
    *(u16x8*)(sB[buf] + (bb ^ 32)) = rb2;
    *(u16x8*)(sB[buf] + (bb ^ 48)) = rb3;
  };
  stage_load(0);
  stage_write(0);
  __syncthreads();
  int cur = 0;
  for (int it = 0; it < 8; ++it) {
    if (it < 7) stage_load((it + 1) * 32);
    int ra = wid * 16 + l15;
    bf16x8 af = *(const bf16x8*)(sA[cur] + ((ra << 6) + (l4 << 4) ^ ((ra & 7) << 4)));
    #pragma unroll
    for (int n4 = 0; n4 < 16; ++n4) {
      int rn = n4 * 16 + l15;
      bf16x8 bf = *(const bf16x8*)(sB[cur] + ((rn << 6) + (l4 << 4) ^ ((rn & 7) << 4)));
      acc[n4] = __builtin_amdgcn_mfma_f32_16x16x32_bf16(af, bf, acc[n4], 0, 0, 0);
    }
    __syncthreads();
    if (it < 7) {
      stage_write(cur ^ 1);
      __syncthreads();
      cur ^= 1;
    }
  }
  const int row = bm + wid * 16 + l4 * 4;
  #pragma unroll
  for (int n4 = 0; n4 < 16; ++n4) {
    int col = n4 * 16 + l15;
    float base = c0[col];
    #pragma unroll
    for (int jj = 0; jj < 4; ++jj)
      Cout[(size_t)(row + jj) * 512 + coff + col] = acc[n4][jj] + base;
  }
}

// ================= batched CSR build =================
struct CooPtrs {
  const int* rw[6];
  const int* cl[6];
  const float* vl[6];
};
static __device__ __forceinline__ void coo_block_resolve(
    int b, int& g, int& eb, int& rb)
{
  if      (b < 1920) { g = 0; eb = 0;    rb = 0; }
  else if (b < 3840) { g = 1; eb = 1920; rb = NN; }
  else if (b < 6080) { g = 2; eb = 3840; rb = 2 * NN; }
  else if (b < 8000) { g = 3; eb = 6080; rb = 2 * NN + MM; }
  else if (b < 9920) { g = 4; eb = 8000; rb = 3 * NN + MM; }
  else               { g = 5; eb = 9920; rb = 4 * NN + MM; }
}

__global__ __launch_bounds__(256) void count_all_kernel(
    CooPtrs coo, int* __restrict__ cnt)
{
  int g, eb, rb;
  coo_block_resolve(blockIdx.x, g, eb, rb);
  int e = (blockIdx.x - eb) * 256 + threadIdx.x;
  atomicAdd(&cnt[rb + coo.rw[g][e]], 1);
}

__global__ __launch_bounds__(256) void scan1_kernel(
    const int* __restrict__ cnt, int* __restrict__ bsum, int n)
{
  __shared__ int sh[256];
  int i = blockIdx.x * 256 + threadIdx.x;
  sh[threadIdx.x] = (i < n) ? cnt[i] : 0;
  __syncthreads();
  for (int off = 128; off; off >>= 1) {
    if (threadIdx.x < off) sh[threadIdx.x] += sh[threadIdx.x + off];
    __syncthreads();
  }
  if (threadIdx.x == 0) bsum[blockIdx.x] = sh[0];
}

__global__ __launch_bounds__(256) void scan2_kernel(int* __restrict__ bsum, int nb)
{
  __shared__ int sh[256];
  int t = threadIdx.x;
  int carry = 0;
  for (int base = 0; base < nb; base += 256) {
    int i = base + t;
    int v = (i < nb) ? bsum[i] : 0;
    sh[t] = v;
    __syncthreads();
    for (int off = 1; off < 256; off <<= 1) {
      int add = (t >= off) ? sh[t - off] : 0;
      __syncthreads();
      sh[t] += add;
      __syncthreads();
    }
    int incl = sh[t];
    int tot = sh[255];
    if (i < nb) bsum[i] = carry + incl - v;
    carry += tot;
    __syncthreads();
  }
}

__global__ __launch_bounds__(256) void scan3_kernel(
    const int* __restrict__ cnt, const int* __restrict__ bsum,
    int* __restrict__ rowptr, int* __restrict__ cntz, int n)
{
  __shared__ int sh[256];
  int i = blockIdx.x * 256 + threadIdx.x;
  int v = (i < n) ? cnt[i] : 0;
  sh[threadIdx.x] = v;
  __syncthreads();
  for (int off = 1; off < 256; off <<= 1) {
    int add = (threadIdx.x >= off) ? sh[threadIdx.x - off] : 0;
    __syncthreads();
    sh[threadIdx.x] += add;
    __syncthreads();
  }
  int incl = sh[threadIdx.x];
  int base = bsum[blockIdx.x];
  if (i < n) { rowptr[i] = base + incl - v; cntz[i] = 0; }
  if (i == n - 1) rowptr[n] = base + incl;
}

__global__ __launch_bounds__(256) void fill_all_kernel(
    CooPtrs coo, const int* __restrict__ P, int* __restrict__ cur,
    int2* __restrict__ epack)
{
  int g, eb, rb;
  coo_block_resolve(blockIdx.x, g, eb, rb);
  int e = (blockIdx.x - eb) * 256 + threadIdx.x;
  int grow = rb + coo.rw[g][e];
  int pos = P[grow] + atomicAdd(&cur[grow], 1);
  epack[pos] = make_int2(coo.cl[g][e], __float_as_int(coo.vl[g][e]));
}

__global__ __launch_bounds__(256) void rowsum_all_kernel(
    const int* __restrict__ P, const int2* __restrict__ epack,
    float* __restrict__ rsAll)
{
  int j = blockIdx.x * 256 + threadIdx.x;
  int g = j / NN;
  int r = j - g * NN;
  int grow = (g == 0 ? 2 * NN + MM : g == 1 ? 3 * NN + MM : 4 * NN + MM) + r;
  float s = 0.0f;
  int end = P[grow + 1];
  for (int e = P[grow]; e < end; ++e) s += __int_as_float(epack[e].y);
  rsAll[j] = s;
}

// ---------------- batched CSR SpMM (3 jobs), wave-per-row -------------------
struct Spmm3 {
  const int* rowptr[3];
  const unsigned short* X[3];
  unsigned short* Y[3];
  float* Y2[3];
  const float* bias[3];
  int src_rows[3];
  int bs1, bs2;
};
__global__ __launch_bounds__(256) void spmm3_kernel(
    Spmm3 s, const int2* __restrict__ ep, int relu)
{
  const int b = blockIdx.x;
  const int j = (b >= s.bs2) ? 2 : (b >= s.bs1 ? 1 : 0);
  const int rblk = b - (j == 2 ? s.bs2 : j == 1 ? s.bs1 : 0);
  const int wave = threadIdx.x >> 6, lane = threadIdx.x & 63;
  const int r = rblk * 4 + wave;
  const int f0 = lane * 4;
  const int src_rows = s.src_rows[j];
  const unsigned short* X = s.X[j];
  const int* rowptr = s.rowptr[j];
  int e = rowptr[r], end = rowptr[r + 1];
  float a0 = 0.0f, a1 = 0.0f, a2 = 0.0f, a3 = 0.0f;
  for (; e + 3 < end; e += 4) {
    int2 cv0 = ep[e], cv1 = ep[e + 1], cv2 = ep[e + 2], cv3 = ep[e + 3];
    ushort4 x0 = {0,0,0,0}, x1 = {0,0,0,0}, x2 = {0,0,0,0}, x3 = {0,0,0,0};
    if (cv0.x < src_rows) x0 = *(const ushort4*)(X + (size_t)cv0.x * DD + f0);
    if (cv1.x < src_rows) x1 = *(const ushort4*)(X + (size_t)cv1.x * DD + f0);
    if (cv2.x < src_rows) x2 = *(const ushort4*)(X + (size_t)cv2.x * DD + f0);
    if (cv3.x < src_rows) x3 = *(const ushort4*)(X + (size_t)cv3.x * DD + f0);
    float v0 = __int_as_float(cv0.y), v1 = __int_as_float(cv1.y);
    float v2 = __int_as_float(cv2.y), v3 = __int_as_float(cv3.y);
    if (cv0.x < src_rows) { a0 += v0*bf2f(x0.x); a1 += v0*bf2f(x0.y); a2 += v0*bf2f(x0.z); a3 += v0*bf2f(x0.w); }
    if (cv1.x < src_rows) { a0 += v1*bf2f(x1.x); a1 += v1*bf2f(x1.y); a2 += v1*bf2f(x1.z); a3 += v1*bf2f(x1.w); }
    if (cv2.x < src_rows) { a0 += v2*bf2f(x2.x); a1 += v2*bf2f(x2.y); a2 += v2*bf2f(x2.z); a3 += v2*bf2f(x2.w); }
    if (cv3.x < src_rows) { a0 += v3*bf2f(x3.x); a1 += v3*bf2f(x3.y); a2 += v3*bf2f(x3.z); a3 += v3*bf2f(x3.w); }
  }
  for (; e < end; ++e) {
    int2 cv = ep[e];
    if (cv.x < src_rows) {
      float v = __int_as_float(cv.y);
      ushort4 xx = *(const ushort4*)(X + (size_t)cv.x * DD + f0);
      a0 += v * bf2f(xx.x); a1 += v * bf2f(xx.y);
      a2 += v * bf2f(xx.z); a3 += v * bf2f(xx.w);
    }
  }
  const float* bias = s.bias[j];
  if (bias) {
    a0 += bias[f0]; a1 += bias[f0 + 1]; a2 += bias[f0 + 2]; a3 += bias[f0 + 3];
  }
  if (relu) {
    a0 = fmaxf(a0, 0.0f); a1 = fmaxf(a1, 0.0f);
    a2 = fmaxf(a2, 0.0f); a3 = fmaxf(a3, 0.0f);
  }
  uint2 yb = { cvtpk(a0, a1), cvtpk(a2, a3) };
  *(uint2*)(s.Y[j] + (size_t)r * DD + f0) = yb;
  if (s.Y2[j]) {
    float4 yf = {a0, a1, a2, a3};
    *(float4*)(s.Y2[j] + (size_t)r * DD + f0) = yf;
  }
}

// ---------------- MFMA flash attention: BOTH MHAs in one dispatch ----------
// P swizzle: r5-r10-proven ^((l15&7)<<4) on write AND read (r11's 32B-granule
// variant REGRESSED: read banks lost bit-4 entropy -> 8-way conflict).
// No barrier after P write: sP is wave-private; lgkmcnt ordering suffices.
__global__ __launch_bounds__(256) void attn2_kernel(
    const unsigned short* __restrict__ Q1, const unsigned short* __restrict__ K1,
    const unsigned short* __restrict__ V1, unsigned short* __restrict__ O1,
    const unsigned short* __restrict__ Q2, const unsigned short* __restrict__ K2,
    const unsigned short* __restrict__ V2, unsigned short* __restrict__ O2)
{
  __shared__ __align__(16) char sKb[4096];
  __shared__ __align__(16) char sVb[4096];
  __shared__ __align__(16) char sPb[8192];
  const int wgid = (blockIdx.x & 7) * 1536 + (blockIdx.x >> 3);
  const int qb = wgid & 15, h = (wgid >> 4) & 7, cc = wgid >> 7;   // cc 0..95
  const int job = cc >= 48;
  const int c = cc - (job ? 48 : 0);
  const unsigned short* Q = job ? Q2 : Q1;
  const unsigned short* K = job ? K2 : K1;
  const unsigned short* V = job ? V2 : V1;
  unsigned short* O = job ? O2 : O1;

  const int tid = threadIdx.x, lane = tid & 63, wid = tid >> 6;
  const int l15 = lane & 15, l4 = lane >> 4;
  char* sPw = sPb + wid * 2048;
  const size_t base = (size_t)c * (CHK * DD) + (size_t)h * DHEAD;
  const int q0 = qb * 64 + wid * 16;

  bf16x8 qf = *(const bf16x8*)(Q + base + (size_t)(q0 + l15) * DD + l4 * 8);

  const int key_s = tid >> 2, dq = (tid & 3) * 8;
  const unsigned short* Kp = K + base + (size_t)key_s * DD + dq;
  const unsigned short* Vp = V + base + (size_t)key_s * DD + dq;
  const int kaddr = ((key_s << 6) + (dq << 1)) ^ ((key_s & 7) << 4);

  f32x4 oacc[2] = {};
  float m = -1e30f, l = 0.0f;
  const f32x4 zero = {};

  for (int kt = 0; kt < CHK; kt += 64) {
    __syncthreads();
    u16x8 kv = *(const u16x8*)Kp;  Kp += 64 * DD;
    u16x8 vv = *(const u16x8*)Vp;  Vp += 64 * DD;
    *(u16x8*)(sKb + kaddr) = kv;
    #pragma unroll
    for (int i = 0; i < 8; ++i) {
      int d = dq + i;
      int bb = ((d << 7) + (key_s << 1))
             ^ ((d & 7) << 4) ^ (((d >> 3) & 3) << 5);
      *(unsigned short*)(sVb + bb) = vv[i];
    }
    __syncthreads();

    f32x4 s[4];
    #pragma unroll
    for (int s4 = 0; s4 < 4; ++s4) {
      int key = s4 * 16 + l15;
      int ba = ((key << 6) + (l4 << 4)) ^ ((key & 7) << 4);
      bf16x8 kf = *(const bf16x8*)(sKb + ba);
      s[s4] = __builtin_amdgcn_mfma_f32_16x16x32_bf16(kf, qf, zero, 0, 0, 0);
    }
    float t0 = max3f(s[0][0], s[0][1], s[0][2]);
    float t1 = max3f(s[0][3], s[1][0], s[1][1]);
    float t2 = max3f(s[1][2], s[1][3], s[2][0]);
    float t3 = max3f(s[2][1], s[2][2], s[2][3]);
    float t4 = max3f(s[3][0], s[3][1], s[3][2]);
    float tmax = max3f(max3f(t0, t1, t2), fmaxf(t3, t4), s[3][3]);
    tmax = fmaxf(tmax, __shfl_xor(tmax, 16));
    tmax = fmaxf(tmax, __shfl_xor(tmax, 32));
    bool skip = __all(tmax - m <= 8.0f);
    float mnew = skip ? m : fmaxf(m, tmax);
    if (!skip) {
      float corr = __builtin_amdgcn_exp2f(m - mnew);
      l *= corr;
      oacc[0] *= corr;
      oacc[1] *= corr;
    }
    float psum = 0.0f;
    float p[4][4];
    #pragma unroll
    for (int s4 = 0; s4 < 4; ++s4)
      #pragma unroll
      for (int j = 0; j < 4; ++j) {
        p[s4][j] = __builtin_amdgcn_exp2f(s[s4][j] - mnew);
        psum += p[s4][j];
      }
    psum += __shfl_xor(psum, 16);
    psum += __shfl_xor(psum, 32);
    l += psum;
    m = mnew;
    // P write: r9 swizzle ^((l15&7)<<4); wave-private buffer -> no barrier
    #pragma unroll
    for (int s4 = 0; s4 < 4; ++s4) {
      uint2 pk = { cvtpk(p[s4][0], p[s4][1]), cvtpk(p[s4][2], p[s4][3]) };
      int bp = ((l15 << 7) + (s4 << 5) + (l4 << 3)) ^ ((l15 & 7) << 4);
      *(uint2*)(sPw + bp) = pk;
    }

    #pragma unroll
    for (int dh = 0; dh < 2; ++dh)
      #pragma unroll
      for (int kh = 0; kh < 2; ++kh) {
        int d = dh * 16 + l15;
        int ba = ((d << 7) + ((kh * 32 + l4 * 8) << 1))
               ^ ((d & 7) << 4) ^ (((d >> 3) & 3) << 5);
        bf16x8 vf = *(const bf16x8*)(sVb + ba);
        int bp = ((l15 << 7) + (kh << 6) + (l4 << 4)) ^ ((l15 & 7) << 4);
        bf16x8 pf = *(const bf16x8*)(sPw + bp);
        oacc[dh] = __builtin_amdgcn_mfma_f32_16x16x32_bf16(vf, pf, oacc[dh], 0, 0, 0);
      }
  }

  float inv = 1.0f / l;
  unsigned short* orow = O + base + (size_t)(q0 + l15) * DD;
  #pragma unroll
  for (int dh = 0; dh < 2; ++dh) {
    uint2 o2 = { cvtpk(oacc[dh][0] * inv, oacc[dh][1] * inv),
                 cvtpk(oacc[dh][2] * inv, oacc[dh][3] * inv) };
    *(uint2*)(orow + dh * 16 + l4 * 4) = o2;
  }
}

__global__ __launch_bounds__(256) void fill_kernel(float* p, long n, float v)
{
  long i = (long)blockIdx.x * 256 + threadIdx.x;
  if (i < n) p[i] = v;
}

extern "C" void kernel_launch(void* const* d_in, const int* in_sizes, int n_in,
                              void* d_out, int out_size, void* d_ws, size_t ws_size,
                              hipStream_t stream)
{
  const float* x     = (const float*)d_in[0];
  const int*   Acg_r = (const int*)d_in[1];
  const int*   Acg_c = (const int*)d_in[2];
  const float* Acg_v = (const float*)d_in[3];
  const int*   Ahy_r = (const int*)d_in[4];
  const int*   Ahy_c = (const int*)d_in[5];
  const float* Ahy_v = (const float*)d_in[6];
  const int*   Asg_r = (const int*)d_in[7];
  const int*   Asg_c = (const int*)d_in[8];
  const float* Asg_v = (const float*)d_in[9];
  const int*   Lcg_r = (const int*)d_in[10];
  const int*   Lcg_c = (const int*)d_in[11];
  const float* Lcg_v = (const float*)d_in[12];
  const int*   Lhy_r = (const int*)d_in[13];
  const int*   Lhy_c = (const int*)d_in[14];
  const float* Lhy_v = (const float*)d_in[15];
  const int*   Lsg_r = (const int*)d_in[16];
  const int*   Lsg_c = (const int*)d_in[17];
  const float* Lsg_v = (const float*)d_in[18];
  const float* cg_W  = (const float*)d_in[19];
  const float* cg_b  = (const float*)d_in[20];
  const float* hg_W  = (const float*)d_in[21];
  const float* hg_b  = (const float*)d_in[22];
  const float* sg_W  = (const float*)d_in[23];
  const float* sg_b  = (const float*)d_in[24];
  const float* snh_W = (const float*)d_in[25];
  const float* snh_b = (const float*)d_in[26];
  const float* snc_W = (const float*)d_in[27];
  const float* snc_b = (const float*)d_in[28];
  const float* sns_W = (const float*)d_in[29];
  const float* sns_b = (const float*)d_in[30];
  const float* spa_hyp_W  = (const float*)d_in[31];
  const float* spa_hyp_b  = (const float*)d_in[32];
  const float* spa_star_W = (const float*)d_in[33];
  const float* spa_star_b = (const float*)d_in[34];
  const float* spa_clq_W  = (const float*)d_in[35];
  const float* spa_clq_b  = (const float*)d_in[36];
  const float* spa_in_w   = (const float*)d_in[37];
  const float* spa_in_b   = (const float*)d_in[38];
  const float* spa_out_w  = (const float*)d_in[39];
  const float* spa_out_b  = (const float*)d_in[40];
  const float* spe_hyp_W  = (const float*)d_in[41];
  const float* spe_hyp_b  = (const float*)d_in[42];
  const float* spe_star_W = (const float*)d_in[43];
  const float* spe_star_b = (const float*)d_in[44];
  const float* spe_clq_W  = (const float*)d_in[45];
  const float* spe_clq_b  = (const float*)d_in[46];
  const float* spe_in_w   = (const float*)d_in[47];
  const float* spe_in_b   = (const float*)d_in[48];
  const float* spe_out_w  = (const float*)d_in[49];
  const float* spe_out_b  = (const float*)d_in[50];

  float* out = (float*)d_out;

  const size_t NF = (size_t)NN * DD;
  const size_t MF = (size_t)MM * DD;
  const size_t WELEMS  = 14u * 65536u;
  const size_t need = (14 * NF + 3 * MF) * 2
                    + (size_t)ETOT * 8
                    + ((size_t)3 * NN + 65536 + 256 + 4096) * 4
                    + ((size_t)ROWS_TOT + 1 + ROWS_TOT + 2048) * 4
                    + WELEMS * 2;

  auto fill = [&](float v) {
    long tot = (long)out_size;
    fill_kernel<<<dim3((unsigned)((tot + 255) / 256)), 256, 0, stream>>>(out, tot, v);
  };
  if (ws_size < need)                        { fill(12.0f); return; }
  if (n_in != 51)                            { fill(16.0f); return; }
  if (in_sizes[0] != NN * FD)                { fill(20.0f); return; }
  if (in_sizes[3] != NEN)                    { fill(24.0f); return; }
  if (in_sizes[9] != NEM)                    { fill(28.0f); return; }
  if (in_sizes[19] != 2 * FD * DD)           { fill(32.0f); return; }
  if (in_sizes[37] != 3 * DD * DD)           { fill(36.0f); return; }
  if (out_size != NN * 512 + NN * DD + EHN * DD) { fill(40.0f); return; }

  // ---- bf16 buffers ----
  unsigned short* Tcg = (unsigned short*)d_ws;
  unsigned short* Thy = Tcg + NF;
  unsigned short* Tsg = Thy + NF;
  unsigned short* Hcg = Tsg + NF;
  unsigned short* Hhy = Hcg + NF;
  unsigned short* Hsg = Hhy + NF;                // M
  unsigned short* Usg = Hsg + MF;                // M
  unsigned short* SG  = Usg + MF;                // M
  unsigned short* CG  = SG + MF;
  unsigned short* HG  = CG + NF;
  unsigned short* LH  = HG + NF;
  unsigned short* LC  = LH + NF;
  unsigned short* LS  = LC + NF;
  unsigned short* QH  = LS + NF;
  unsigned short* KH  = QH + NF;
  unsigned short* VH  = KH + NF;
  unsigned short* AOx = VH + NF;
  unsigned short* Ucg = Tcg;
  unsigned short* Uhy = Thy;
  unsigned short* Q2  = LH;
  unsigned short* K2  = LC;
  unsigned short* V2  = LS;
  unsigned short* AO1 = Hcg;
  unsigned short* AO2 = Hhy;
  (void)AOx;

  int2* epack = (int2*)(AOx + NF);
  float* fp = (float*)(epack + ETOT);
  float* rsAll = fp;           fp += 3 * NN;
  float* tmp256 = fp;          fp += 65536;
  float* tmpv = fp;            fp += 256;
  float* CB = fp;              fp += 4096;
  int* P    = (int*)fp;
  int* cnt  = P + ROWS_TOT + 1;
  int* bsum = cnt + ROWS_TOT;
  unsigned short* WB = (unsigned short*)(bsum + 2048);

  int* rp_cg  = P;
  int* rp_hy  = P + NN;
  int* rp_sg  = P + 2 * NN;
  int* rp_Lcg = P + 2 * NN + MM;
  int* rp_Lhy = P + 3 * NN + MM;
  int* rp_Lsg = P + 4 * NN + MM;
  float* rs_c = rsAll;
  float* rs_h = rsAll + NN;
  float* rs_s = rsAll + 2 * NN;

  auto wslot = [&](int s) { return WB + (size_t)s * 65536; };
  auto cb    = [&](int s) { return CB + (size_t)s * 256; };

  auto combine = [&](const float* Bw, const float* Aw, const float* ab,
                     const float* bb, unsigned short* Wc, float* bcp, float fs) {
    combine_w_kernel<<<dim3(256), 256, 0, stream>>>(Bw, Aw, ab, bb, Wc, bcp, fs);
  };
  auto combine3 = [&](const float* w3, const float* b3, const float* pW,
                      const float* pb, const float* sW, const float* sb,
                      unsigned short* Wc, float* cvecp, float* c0p, float fs) {
    mm256f_kernel<<<dim3(256), 256, 0, stream>>>(pW, sW, tmp256);
    mm256b_kernel<<<dim3(256), 256, 0, stream>>>(w3, tmp256, Wc, fs);
    mv256_kernel<<<dim3(1), 256, 0, stream>>>(pW, sb, nullptr, tmpv, 1.0f);
    mv256_kernel<<<dim3(1), 256, 0, stream>>>(w3, tmpv, nullptr, cvecp, fs);
    mv256_kernel<<<dim3(1), 256, 0, stream>>>(w3, pb, b3, c0p, fs);
  };

  const float fsQ = 0.17677669529663687f * 1.4426950408889634f;

  // ================= weight prep =================
  {
    CastJobs jobs;
    jobs.src[0] = cg_W;           jobs.dst[0] = wslot(0);  jobs.trans[0] = 1;
    jobs.src[1] = cg_W + FD * DD; jobs.dst[1] = wslot(1);  jobs.trans[1] = 1;
    jobs.src[2] = hg_W;           jobs.dst[2] = wslot(2);  jobs.trans[2] = 1;
    jobs.src[3] = hg_W + FD * DD; jobs.dst[3] = wslot(3);  jobs.trans[3] = 1;
    jobs.src[4] = sg_W;           jobs.dst[4] = wslot(4);  jobs.trans[4] = 1;
    jobs.src[5] = sg_W + FD * DD; jobs.dst[5] = wslot(5);  jobs.trans[5] = 1;
    jobs.src[6] = spa_out_w;      jobs.dst[6] = wslot(12); jobs.trans[6] = 0;
    jobs.src[7] = spe_out_w;      jobs.dst[7] = wslot(13); jobs.trans[7] = 0;
    cast_w8_kernel<<<dim3(8 * 256), 256, 0, stream>>>(jobs);
  }
  combine(spa_in_w,                spa_hyp_W,  spa_hyp_b,  spa_in_b,          wslot(6), cb(0), fsQ);
  combine(spa_in_w + DD * DD,      spa_star_W, spa_star_b, spa_in_b + DD,     wslot(7), cb(1), 1.0f);
  combine(spa_in_w + 2 * DD * DD,  spa_clq_W,  spa_clq_b,  spa_in_b + 2 * DD, wslot(8), cb(2), 1.0f);
  combine3(spe_in_w,               spe_in_b,            spe_hyp_W,  spe_hyp_b,  snh_W, snh_b, wslot(9),  cb(3), cb(4), fsQ);
  combine3(spe_in_w + DD * DD,     spe_in_b + DD,       spe_star_W, spe_star_b, snc_W, snc_b, wslot(10), cb(5), cb(6), 1.0f);
  combine3(spe_in_w + 2 * DD * DD, spe_in_b + 2 * DD,   spe_clq_W,  spe_clq_b,  sns_W, sns_b, wslot(11), cb(7), cb(8), 1.0f);

  // ================= batched CSR build =================
  {
    CooPtrs coo;
    coo.rw[0] = Acg_r; coo.cl[0] = Acg_c; coo.vl[0] = Acg_v;
    coo.rw[1] = Ahy_r; coo.cl[1] = Ahy_c; coo.vl[1] = Ahy_v;
    coo.rw[2] = Asg_r; coo.cl[2] = Asg_c; coo.vl[2] = Asg_v;
    coo.rw[3] = Lcg_r; coo.cl[3] = Lcg_c; coo.vl[3] = Lcg_v;
    coo.rw[4] = Lhy_r; coo.cl[4] = Lhy_c; coo.vl[4] = Lhy_v;
    coo.rw[5] = Lsg_r; coo.cl[5] = Lsg_c; coo.vl[5] = Lsg_v;
    hipMemsetAsync(cnt, 0, (size_t)ROWS_TOT * 4, stream);
    count_all_kernel<<<dim3(ETOT / 256), 256, 0, stream>>>(coo, cnt);
    scan1_kernel<<<dim3(ROWS_TOT / 256), 256, 0, stream>>>(cnt, bsum, ROWS_TOT);
    scan2_kernel<<<dim3(1), 256, 0, stream>>>(bsum, ROWS_TOT / 256);
    scan3_kernel<<<dim3(ROWS_TOT / 256), 256, 0, stream>>>(cnt, bsum, P, cnt, ROWS_TOT);
    fill_all_kernel<<<dim3(ETOT / 256), 256, 0, stream>>>(coo, P, cnt, epack);
    rowsum_all_kernel<<<dim3(3 * NN / 256), 256, 0, stream>>>(P, epack, rsAll);
  }

  // ================= expansion nets (batched x3) =================
  {
    Gemm3 g = {};
    for (int j = 0; j < 3; ++j) { g.A[j] = x; g.c0[j] = nullptr; g.rs[j] = nullptr; }
    g.W[0] = wslot(0); g.out[0] = Tcg;
    g.W[1] = wslot(2); g.out[1] = Thy;
    g.W[2] = wslot(4); g.out[2] = Tsg;
    g.bs1 = 768; g.bs2 = 1536; g.btot = 2304;
    gemm3_kernel<0><<<dim3(2304), 256, 0, stream>>>(g);
  }
  {
    Spmm3 s = {};
    s.rowptr[0] = rp_cg; s.X[0] = Tcg; s.Y[0] = Hcg; s.Y2[0] = nullptr; s.bias[0] = cg_b; s.src_rows[0] = NN;
    s.rowptr[1] = rp_hy; s.X[1] = Thy; s.Y[1] = Hhy; s.Y2[1] = nullptr; s.bias[1] = hg_b; s.src_rows[1] = NN;
    s.rowptr[2] = rp_sg; s.X[2] = Tsg; s.Y[2] = Hsg; s.Y2[2] = nullptr; s.bias[2] = sg_b; s.src_rows[2] = NN;
    s.bs1 = NN / 4; s.bs2 = 2 * (NN / 4);
    spmm3_kernel<<<dim3(2 * (NN / 4) + MM / 4), 256, 0, stream>>>(s, epack, 1);
  }
  {
    Gemm3 g = {};
    g.A[0] = Hcg; g.W[0] = wslot(1); g.out[0] = Ucg;
    g.A[1] = Hhy; g.W[1] = wslot(3); g.out[1] = Uhy;
    g.A[2] = Hsg; g.W[2] = wslot(5); g.out[2] = Usg;
    for (int j = 0; j < 3; ++j) { g.c0[j] = nullptr; g.rs[j] = nullptr; }
    g.bs1 = NN / 64; g.bs2 = 2 * (NN / 64); g.btot = 2 * (NN / 64) + MM / 64;
    gemm3_kernel<1><<<dim3(2 * (NN / 64) + MM / 64), 256, 0, stream>>>(g);
  }
  {
    Spmm3 s = {};
    s.rowptr[0] = rp_cg; s.X[0] = Ucg; s.Y[0] = CG; s.Y2[0] = nullptr; s.bias[0] = cg_b + DD; s.src_rows[0] = NN;
    s.rowptr[1] = rp_hy; s.X[1] = Uhy; s.Y[1] = HG; s.Y2[1] = nullptr; s.bias[1] = hg_b + DD; s.src_rows[1] = NN;
    s.rowptr[2] = rp_sg; s.X[2] = Usg; s.Y[2] = SG; s.Y2[2] = out + (size_t)NN * 512; s.bias[2] = sg_b + DD; s.src_rows[2] = MM;
    s.bs1 = NN / 4; s.bs2 = 2 * (NN / 4);
    spmm3_kernel<<<dim3(2 * (NN / 4) + MM / 4), 256, 0, stream>>>(s, epack, 0);
  }
  {
    Spmm3 s = {};
    s.rowptr[0] = rp_Lhy; s.X[0] = HG; s.Y[0] = LH; s.Y2[0] = nullptr; s.bias[0] = nullptr; s.src_rows[0] = NN;
    s.rowptr[1] = rp_Lcg; s.X[1] = CG; s.Y[1] = LC; s.Y2[1] = nullptr; s.bias[1] = nullptr; s.src_rows[1] = NN;
    s.rowptr[2] = rp_Lsg; s.X[2] = SG; s.Y[2] = LS; s.Y2[2] = nullptr; s.bias[2] = nullptr; s.src_rows[2] = MM;
    s.bs1 = NN / 4; s.bs2 = 2 * (NN / 4);
    spmm3_kernel<<<dim3(3 * (NN / 4)), 256, 0, stream>>>(s, epack, 0);
  }

  // ================= both MHAs =================
  {  // spectral QKV: LH/LC/LS -> QH/KH/VH
    Gemm3 g = {};
    g.A[0] = LH; g.W[0] = wslot(9);  g.c0[0] = cb(4); g.rs[0] = rs_h; g.cvec[0] = cb(3); g.out[0] = QH;
    g.A[1] = LC; g.W[1] = wslot(10); g.c0[1] = cb(6); g.rs[1] = rs_c; g.cvec[1] = cb(5); g.out[1] = KH;
    g.A[2] = LS; g.W[2] = wslot(11); g.c0[2] = cb(8); g.rs[2] = rs_s; g.cvec[2] = cb(7); g.out[2] = VH;
    g.bs1 = 768; g.bs2 = 1536; g.btot = 2304;
    gemm3_kernel<1><<<dim3(2304), 256, 0, stream>>>(g);
  }
  {  // spatial QKV: HG/CG/SG -> Q2/K2/V2 (reuse dead LH/LC/LS)
    Gemm3 g = {};
    g.A[0] = HG; g.W[0] = wslot(6); g.c0[0] = cb(0); g.rs[0] = nullptr; g.out[0] = Q2;
    g.A[1] = CG; g.W[1] = wslot(7); g.c0[1] = cb(1); g.rs[1] = nullptr; g.out[1] = K2;
    g.A[2] = SG; g.W[2] = wslot(8); g.c0[2] = cb(2); g.rs[2] = nullptr; g.out[2] = V2;
    g.bs1 = 768; g.bs2 = 1536; g.btot = 2304;
    gemm3_kernel<1><<<dim3(2304), 256, 0, stream>>>(g);
  }
  attn2_kernel<<<dim3(12288), 256, 0, stream>>>(QH, KH, VH, AO1,
                                                Q2, K2, V2, AO2);
  gemmout2_kernel<<<dim3(2 * (NN / 64)), 256, 0, stream>>>(
      AO1, wslot(13), spe_out_b,       // job0: spectral -> taa cols 256..511
      AO2, wslot(12), spa_out_b,       // job1: spatial  -> taa cols 0..255
      out);
}

// Round 13
// 1567.766 us; speedup vs baseline: 1.0412x; 1.0170x over previous
//
#include <hip/hip_runtime.h>

// Problem dims (fixed by reference)
#define NN 49152
#define EHN 8192
#define MM (NN + EHN)       // 57344
#define FD 256
#define DD 256
#define NHEADS 8
#define DHEAD 32
#define CHK 1024
#define NEN (10 * NN)       // 491520
#define NEM (10 * MM)       // 573440
#define ROWS_TOT (4 * NN + 2 * MM)   // 311296
#define ETOT (4 * NEN + 2 * NEM)     // 3,112,960

typedef __bf16 bf16x8 __attribute__((ext_vector_type(8)));
typedef unsigned short u16x8 __attribute__((ext_vector_type(8)));
typedef float f32x4 __attribute__((ext_vector_type(4)));

static __device__ __forceinline__ unsigned short f2bf(float f) {
  unsigned int u = __float_as_uint(f);
  unsigned int r = (u + 0x7FFFu + ((u >> 16) & 1u)) >> 16;
  return (unsigned short)r;
}
static __device__ __forceinline__ float bf2f(unsigned short u) {
  return __uint_as_float((unsigned int)u << 16);
}
static __device__ __forceinline__ unsigned int cvtpk(float a, float b) {
  unsigned int r;
  asm("v_cvt_pk_bf16_f32 %0, %1, %2" : "=v"(r) : "v"(a), "v"(b));
  return r;
}
static __device__ __forceinline__ float max3f(float a, float b, float c) {
  return fmaxf(fmaxf(a, b), c);   // clang fuses to v_max3_f32
}

// ---------------- weight prep ----------------
struct CastJobs {
  const float* src[8];
  unsigned short* dst[8];
  int trans[8];
};
__global__ __launch_bounds__(256) void cast_w8_kernel(CastJobs jobs)
{
  int job = blockIdx.x >> 8;
  int i = (blockIdx.x & 255) * 256 + threadIdx.x;
  int n = i >> 8, k = i & 255;
  const float* src = jobs.src[job];
  float f = jobs.trans[job] ? src[(size_t)k * 256 + n] : src[i];
  jobs.dst[job][i] = f2bf(f);
}

__global__ __launch_bounds__(256) void combine_w_kernel(
    const float* __restrict__ Bw, const float* __restrict__ Aw,
    const float* __restrict__ ab, const float* __restrict__ bb,
    unsigned short* __restrict__ Wc, float* __restrict__ bc, float fscale)
{
  int n = blockIdx.x, t = threadIdx.x;
  __shared__ float shB[256];
  __shared__ float red[256];
  shB[t] = Bw[n * 256 + t];
  __syncthreads();
  float acc = 0.0f;
  #pragma unroll 8
  for (int j = 0; j < 256; ++j) acc += shB[j] * Aw[j * 256 + t];
  Wc[n * 256 + t] = f2bf(acc * fscale);
  red[t] = shB[t] * ab[t];
  __syncthreads();
  for (int off = 128; off; off >>= 1) {
    if (t < off) red[t] += red[t + off];
    __syncthreads();
  }
  if (t == 0) bc[n] = (red[0] + bb[n]) * fscale;
}

__global__ __launch_bounds__(256) void mm256f_kernel(
    const float* __restrict__ A, const float* __restrict__ B,
    float* __restrict__ C)
{
  int n = blockIdx.x, t = threadIdx.x;
  __shared__ float sa[256];
  sa[t] = A[n * 256 + t];
  __syncthreads();
  float acc = 0.0f;
  #pragma unroll 8
  for (int j = 0; j < 256; ++j) acc += sa[j] * B[j * 256 + t];
  C[n * 256 + t] = acc;
}

__global__ __launch_bounds__(256) void mm256b_kernel(
    const float* __restrict__ A, const float* __restrict__ B,
    unsigned short* __restrict__ W, float fs)
{
  int n = blockIdx.x, t = threadIdx.x;
  __shared__ float sa[256];
  sa[t] = A[n * 256 + t];
  __syncthreads();
  float acc = 0.0f;
  #pragma unroll 8
  for (int j = 0; j < 256; ++j) acc += sa[j] * B[j * 256 + t];
  W[n * 256 + t] = f2bf(acc * fs);
}

__global__ __launch_bounds__(256) void mv256_kernel(
    const float* __restrict__ W, const float* __restrict__ v,
    const float* __restrict__ add, float* __restrict__ outv, float fs)
{
  int t = threadIdx.x;
  __shared__ float sv[256];
  sv[t] = v[t];
  __syncthreads();
  float acc = 0.0f;
  #pragma unroll 8
  for (int k = 0; k < 256; ++k) acc += W[t * 256 + k] * sv[k];
  if (add) acc += add[t];
  outv[t] = fs * acc;
}

// ---------------- batched bf16-MFMA GEMM (3 jobs, bf16 out) ----------------
struct Gemm3 {
  const void* A[3];
  const unsigned short* W[3];
  const float* c0[3];
  const float* rs[3];
  const float* cvec[3];
  unsigned short* out[3];
  int bs1, bs2, btot;
};
template<int ABF>
__global__ __launch_bounds__(256) void gemm3_kernel(Gemm3 g)
{
  const int b = blockIdx.x;
  const int j = (b >= g.bs2) ? 2 : (b >= g.bs1 ? 1 : 0);
  const int bm = (b - (j == 2 ? g.bs2 : j == 1 ? g.bs1 : 0)) * 64;
  const void* Ain = g.A[j];
  const unsigned short* Wt = g.W[j];

  __shared__ __align__(16) char sA[2][4096];
  __shared__ __align__(16) char sB[2][16384];
  const int tid = threadIdx.x, lane = tid & 63, wid = tid >> 6;
  const int l15 = lane & 15, l4 = lane >> 4;

  f32x4 acc[16] = {};
  const int ar = tid >> 2, akq = (tid & 3) * 8;
  const int bn = tid;

  float4 fa0, fa1;
  u16x8 ua;
  u16x8 rb0, rb1, rb2, rb3;
  auto stage_load = [&](int k0) {
    if (ABF) {
      ua = *(const u16x8*)((const unsigned short*)Ain +
                           (size_t)(bm + ar) * 256 + k0 + akq);
    } else {
      const float* ap = (const float*)Ain + (size_t)(bm + ar) * 256 + k0 + akq;
      fa0 = *(const float4*)ap;
      fa1 = *(const float4*)(ap + 4);
    }
    const unsigned short* bp = Wt + (size_t)bn * 256 + k0;
    rb0 = *(const u16x8*)bp;        rb1 = *(const u16x8*)(bp + 8);
    rb2 = *(const u16x8*)(bp + 16); rb3 = *(const u16x8*)(bp + 24);
  };
  auto stage_write = [&](int buf) {
    u16x8 va;
    if (ABF) {
      va = ua;
    } else {
      va[0] = f2bf(fa0.x); va[1] = f2bf(fa0.y); va[2] = f2bf(fa0.z); va[3] = f2bf(fa0.w);
      va[4] = f2bf(fa1.x); va[5] = f2bf(fa1.y); va[6] = f2bf(fa1.z); va[7] = f2bf(fa1.w);
    }
    int aa = ((ar << 6) + (akq << 1)) ^ ((ar & 7) << 4);
    *(u16x8*)(sA[buf] + aa) = va;
    int bb = (bn << 6) ^ ((bn & 7) << 4);
    *(u16x8*)(sB[buf] + bb) = rb0;
    *(u16x8*)(sB[buf] + (bb ^ 16)) = rb1;
    *(u16x8*)(sB[buf] + (bb ^ 32)) = rb2;
    *(u16x8*)(sB[buf] + (bb ^ 48)) = rb3;
  };

  stage_load(0);
  stage_write(0);
  __syncthreads();
  int cur = 0;
  for (int it = 0; it < 8; ++it) {
    if (it < 7) stage_load((it + 1) * 32);
    int ra = wid * 16 + l15;
    bf16x8 af = *(const bf16x8*)(sA[cur] + ((ra << 6) + (l4 << 4) ^ ((ra & 7) << 4)));
    #pragma unroll
    for (int n4 = 0; n4 < 16; ++n4) {
      int rn = n4 * 16 + l15;
      bf16x8 bf = *(const bf16x8*)(sB[cur] + ((rn << 6) + (l4 << 4) ^ ((rn & 7) << 4)));
      acc[n4] = __builtin_amdgcn_mfma_f32_16x16x32_bf16(af, bf, acc[n4], 0, 0, 0);
    }
    __syncthreads();
    if (it < 7) {
      stage_write(cur ^ 1);
      __syncthreads();
      cur ^= 1;
    }
  }
  const int row = bm + wid * 16 + l4 * 4;
  const float* rs = g.rs[j];
  const float* c0 = g.c0[j];
  const float* cvec = g.cvec[j];
  unsigned short* Cout = g.out[j];
  float rsv[4];
  if (rs) {
    #pragma unroll
    for (int jj = 0; jj < 4; ++jj) rsv[jj] = rs[row + jj];
  }
  #pragma unroll
  for (int n4 = 0; n4 < 16; ++n4) {
    int col = n4 * 16 + l15;
    float base = c0 ? c0[col] : 0.0f;
    float cv = rs ? cvec[col] : 0.0f;
    #pragma unroll
    for (int jj = 0; jj < 4; ++jj) {
      float v = acc[n4][jj] + base;
      if (rs) v += rsv[jj] * cv;
      Cout[(size_t)(row + jj) * 256 + col] = f2bf(v);
    }
  }
}

// batched out-projection GEMM (2 jobs, fp32 strided out into taa halves)
__global__ __launch_bounds__(256) void gemmout2_kernel(
    const unsigned short* __restrict__ A0, const unsigned short* __restrict__ W0,
    const float* __restrict__ b0,
    const unsigned short* __restrict__ A1, const unsigned short* __restrict__ W1,
    const float* __restrict__ b1,
    float* __restrict__ Cout)
{
  const int job = blockIdx.x >= (NN / 64);
  const int bm = (blockIdx.x - (job ? NN / 64 : 0)) * 64;
  const unsigned short* Ain = job ? A1 : A0;
  const unsigned short* Wt  = job ? W1 : W0;
  const float* c0 = job ? b1 : b0;
  const int coff = job ? 0 : 256;

  __shared__ __align__(16) char sA[2][4096];
  __shared__ __align__(16) char sB[2][16384];
  const int tid = threadIdx.x, lane = tid & 63, wid = tid >> 6;
  const int l15 = lane & 15, l4 = lane >> 4;

  f32x4 acc[16] = {};
  const int ar = tid >> 2, akq = (tid & 3) * 8;
  const int bn = tid;
  u16x8 ua, rb0, rb1, rb2, rb3;
  auto stage_load = [&](int k0) {
    ua = *(const u16x8*)(Ain + (size_t)(bm + ar) * 256 + k0 + akq);
    const unsigned short* bp = Wt + (size_t)bn * 256 + k0;
    rb0 = *(const u16x8*)bp;        rb1 = *(const u16x8*)(bp + 8);
    rb2 = *(const u16x8*)(bp + 16); rb3 = *(const u16x8*)(bp + 24);
  };
  auto stage_write = [&](int buf) {
    int aa = ((ar << 6) + (akq << 1)) ^ ((ar & 7) << 4);
    *(u16x8*)(sA[buf] + aa) = ua;
    int bb = (bn << 6) ^ ((bn & 7) << 4);
    *(u16x8*)(sB[buf] + bb) = rb0;
    *(u16x8*)(sB[buf] + (bb ^ 16)) = rb1;
    *(u16x8*)(sB[buf] + (bb ^ 32)) = rb2;
    *(u16x8*)(sB[buf] + (bb ^ 48)) = rb3;
  };
  stage_load(0);
  stage_write(0);
  __syncthreads();
  int cur = 0;
  for (int it = 0; it < 8; ++it) {
    if (it < 7) stage_load((it + 1) * 32);
    int ra = wid * 16 + l15;
    bf16x8 af = *(const bf16x8*)(sA[cur] + ((ra << 6) + (l4 << 4) ^ ((ra & 7) << 4)));
    #pragma unroll
    for (int n4 = 0; n4 < 16; ++n4) {
      int rn = n4 * 16 + l15;
      bf16x8 bf = *(const bf16x8*)(sB[cur] + ((rn << 6) + (l4 << 4) ^ ((rn & 7) << 4)));
      acc[n4] = __builtin_amdgcn_mfma_f32_16x16x32_bf16(af, bf, acc[n4], 0, 0, 0);
    }
    __syncthreads();
    if (it < 7) {
      stage_write(cur ^ 1);
      __syncthreads();
      cur ^= 1;
    }
  }
  const int row = bm + wid * 16 + l4 * 4;
  #pragma unroll
  for (int n4 = 0; n4 < 16; ++n4) {
    int col = n4 * 16 + l15;
    float base = c0[col];
    #pragma unroll
    for (int jj = 0; jj < 4; ++jj)
      Cout[(size_t)(row + jj) * 512 + coff + col] = acc[n4][jj] + base;
  }
}

// ================= batched CSR build =================
struct CooPtrs {
  const int* rw[6];
  const int* cl[6];
  const float* vl[6];
};
static __device__ __forceinline__ void coo_block_resolve(
    int b, int& g, int& eb, int& rb)
{
  if      (b < 1920) { g = 0; eb = 0;    rb = 0; }
  else if (b < 3840) { g = 1; eb = 1920; rb = NN; }
  else if (b < 6080) { g = 2; eb = 3840; rb = 2 * NN; }
  else if (b < 8000) { g = 3; eb = 6080; rb = 2 * NN + MM; }
  else if (b < 9920) { g = 4; eb = 8000; rb = 3 * NN + MM; }
  else               { g = 5; eb = 9920; rb = 4 * NN + MM; }
}

__global__ __launch_bounds__(256) void count_all_kernel(
    CooPtrs coo, int* __restrict__ cnt)
{
  int g, eb, rb;
  coo_block_resolve(blockIdx.x, g, eb, rb);
  int e = (blockIdx.x - eb) * 256 + threadIdx.x;
  atomicAdd(&cnt[rb + coo.rw[g][e]], 1);
}

__global__ __launch_bounds__(256) void scan1_kernel(
    const int* __restrict__ cnt, int* __restrict__ bsum, int n)
{
  __shared__ int sh[256];
  int i = blockIdx.x * 256 + threadIdx.x;
  sh[threadIdx.x] = (i < n) ? cnt[i] : 0;
  __syncthreads();
  for (int off = 128; off; off >>= 1) {
    if (threadIdx.x < off) sh[threadIdx.x] += sh[threadIdx.x + off];
    __syncthreads();
  }
  if (threadIdx.x == 0) bsum[blockIdx.x] = sh[0];
}

__global__ __launch_bounds__(256) void scan2_kernel(int* __restrict__ bsum, int nb)
{
  __shared__ int sh[256];
  int t = threadIdx.x;
  int carry = 0;
  for (int base = 0; base < nb; base += 256) {
    int i = base + t;
    int v = (i < nb) ? bsum[i] : 0;
    sh[t] = v;
    __syncthreads();
    for (int off = 1; off < 256; off <<= 1) {
      int add = (t >= off) ? sh[t - off] : 0;
      __syncthreads();
      sh[t] += add;
      __syncthreads();
    }
    int incl = sh[t];
    int tot = sh[255];
    if (i < nb) bsum[i] = carry + incl - v;
    carry += tot;
    __syncthreads();
  }
}

__global__ __launch_bounds__(256) void scan3_kernel(
    const int* __restrict__ cnt, const int* __restrict__ bsum,
    int* __restrict__ rowptr, int* __restrict__ cntz, int n)
{
  __shared__ int sh[256];
  int i = blockIdx.x * 256 + threadIdx.x;
  int v = (i < n) ? cnt[i] : 0;
  sh[threadIdx.x] = v;
  __syncthreads();
  for (int off = 1; off < 256; off <<= 1) {
    int add = (threadIdx.x >= off) ? sh[threadIdx.x - off] : 0;
    __syncthreads();
    sh[threadIdx.x] += add;
    __syncthreads();
  }
  int incl = sh[threadIdx.x];
  int base = bsum[blockIdx.x];
  if (i < n) { rowptr[i] = base + incl - v; cntz[i] = 0; }
  if (i == n - 1) rowptr[n] = base + incl;
}

__global__ __launch_bounds__(256) void fill_all_kernel(
    CooPtrs coo, const int* __restrict__ P, int* __restrict__ cur,
    int2* __restrict__ epack)
{
  int g, eb, rb;
  coo_block_resolve(blockIdx.x, g, eb, rb);
  int e = (blockIdx.x - eb) * 256 + threadIdx.x;
  int grow = rb + coo.rw[g][e];
  int pos = P[grow] + atomicAdd(&cur[grow], 1);
  epack[pos] = make_int2(coo.cl[g][e], __float_as_int(coo.vl[g][e]));
}

__global__ __launch_bounds__(256) void rowsum_all_kernel(
    const int* __restrict__ P, const int2* __restrict__ epack,
    float* __restrict__ rsAll)
{
  int j = blockIdx.x * 256 + threadIdx.x;
  int g = j / NN;
  int r = j - g * NN;
  int grow = (g == 0 ? 2 * NN + MM : g == 1 ? 3 * NN + MM : 4 * NN + MM) + r;
  float s = 0.0f;
  int end = P[grow + 1];
  for (int e = P[grow]; e < end; ++e) s += __int_as_float(epack[e].y);
  rsAll[j] = s;
}

// ---------------- batched CSR SpMM (3 jobs), wave-per-row -------------------
struct Spmm3 {
  const int* rowptr[3];
  const unsigned short* X[3];
  unsigned short* Y[3];
  float* Y2[3];
  const float* bias[3];
  int src_rows[3];
  int bs1, bs2;
};
__global__ __launch_bounds__(256) void spmm3_kernel(
    Spmm3 s, const int2* __restrict__ ep, int relu)
{
  const int b = blockIdx.x;
  const int j = (b >= s.bs2) ? 2 : (b >= s.bs1 ? 1 : 0);
  const int rblk = b - (j == 2 ? s.bs2 : j == 1 ? s.bs1 : 0);
  const int wave = threadIdx.x >> 6, lane = threadIdx.x & 63;
  const int r = rblk * 4 + wave;
  const int f0 = lane * 4;
  const int src_rows = s.src_rows[j];
  const unsigned short* X = s.X[j];
  const int* rowptr = s.rowptr[j];
  int e = rowptr[r], end = rowptr[r + 1];
  float a0 = 0.0f, a1 = 0.0f, a2 = 0.0f, a3 = 0.0f;
  for (; e + 3 < end; e += 4) {
    int2 cv0 = ep[e], cv1 = ep[e + 1], cv2 = ep[e + 2], cv3 = ep[e + 3];
    ushort4 x0 = {0,0,0,0}, x1 = {0,0,0,0}, x2 = {0,0,0,0}, x3 = {0,0,0,0};
    if (cv0.x < src_rows) x0 = *(const ushort4*)(X + (size_t)cv0.x * DD + f0);
    if (cv1.x < src_rows) x1 = *(const ushort4*)(X + (size_t)cv1.x * DD + f0);
    if (cv2.x < src_rows) x2 = *(const ushort4*)(X + (size_t)cv2.x * DD + f0);
    if (cv3.x < src_rows) x3 = *(const ushort4*)(X + (size_t)cv3.x * DD + f0);
    float v0 = __int_as_float(cv0.y), v1 = __int_as_float(cv1.y);
    float v2 = __int_as_float(cv2.y), v3 = __int_as_float(cv3.y);
    if (cv0.x < src_rows) { a0 += v0*bf2f(x0.x); a1 += v0*bf2f(x0.y); a2 += v0*bf2f(x0.z); a3 += v0*bf2f(x0.w); }
    if (cv1.x < src_rows) { a0 += v1*bf2f(x1.x); a1 += v1*bf2f(x1.y); a2 += v1*bf2f(x1.z); a3 += v1*bf2f(x1.w); }
    if (cv2.x < src_rows) { a0 += v2*bf2f(x2.x); a1 += v2*bf2f(x2.y); a2 += v2*bf2f(x2.z); a3 += v2*bf2f(x2.w); }
    if (cv3.x < src_rows) { a0 += v3*bf2f(x3.x); a1 += v3*bf2f(x3.y); a2 += v3*bf2f(x3.z); a3 += v3*bf2f(x3.w); }
  }
  for (; e < end; ++e) {
    int2 cv = ep[e];
    if (cv.x < src_rows) {
      float v = __int_as_float(cv.y);
      ushort4 xx = *(const ushort4*)(X + (size_t)cv.x * DD + f0);
      a0 += v * bf2f(xx.x); a1 += v * bf2f(xx.y);
      a2 += v * bf2f(xx.z); a3 += v * bf2f(xx.w);
    }
  }
  const float* bias = s.bias[j];
  if (bias) {
    a0 += bias[f0]; a1 += bias[f0 + 1]; a2 += bias[f0 + 2]; a3 += bias[f0 + 3];
  }
  if (relu) {
    a0 = fmaxf(a0, 0.0f); a1 = fmaxf(a1, 0.0f);
    a2 = fmaxf(a2, 0.0f); a3 = fmaxf(a3, 0.0f);
  }
  uint2 yb = { cvtpk(a0, a1), cvtpk(a2, a3) };
  *(uint2*)(s.Y[j] + (size_t)r * DD + f0) = yb;
  if (s.Y2[j]) {
    float4 yf = {a0, a1, a2, a3};
    *(float4*)(s.Y2[j] + (size_t)r * DD + f0) = yf;
  }
}

// ---------------- MFMA flash attention: BOTH MHAs, T14 async-stage ----------
// Per tile: barrier -> LDS write (from regs, tile t) -> barrier -> ISSUE tile
// t+1 global loads -> compute (QK/softmax/PV hides the load latency).
__global__ __launch_bounds__(256) void attn2_kernel(
    const unsigned short* __restrict__ Q1, const unsigned short* __restrict__ K1,
    const unsigned short* __restrict__ V1, unsigned short* __restrict__ O1,
    const unsigned short* __restrict__ Q2, const unsigned short* __restrict__ K2,
    const unsigned short* __restrict__ V2, unsigned short* __restrict__ O2)
{
  __shared__ __align__(16) char sKb[4096];
  __shared__ __align__(16) char sVb[4096];
  __shared__ __align__(16) char sPb[8192];
  const int wgid = (blockIdx.x & 7) * 1536 + (blockIdx.x >> 3);
  const int qb = wgid & 15, h = (wgid >> 4) & 7, cc = wgid >> 7;   // cc 0..95
  const int job = cc >= 48;
  const int c = cc - (job ? 48 : 0);
  const unsigned short* Q = job ? Q2 : Q1;
  const unsigned short* K = job ? K2 : K1;
  const unsigned short* V = job ? V2 : V1;
  unsigned short* O = job ? O2 : O1;

  const int tid = threadIdx.x, lane = tid & 63, wid = tid >> 6;
  const int l15 = lane & 15, l4 = lane >> 4;
  char* sPw = sPb + wid * 2048;
  const size_t base = (size_t)c * (CHK * DD) + (size_t)h * DHEAD;
  const int q0 = qb * 64 + wid * 16;

  bf16x8 qf = *(const bf16x8*)(Q + base + (size_t)(q0 + l15) * DD + l4 * 8);

  const int key_s = tid >> 2, dq = (tid & 3) * 8;
  const unsigned short* Kp = K + base + (size_t)key_s * DD + dq;
  const unsigned short* Vp = V + base + (size_t)key_s * DD + dq;
  const int kaddr = ((key_s << 6) + (dq << 1)) ^ ((key_s & 7) << 4);

  f32x4 oacc[2] = {};
  float m = -1e30f, l = 0.0f;
  const f32x4 zero = {};

  // prologue: tile-0 staging regs
  u16x8 kv = *(const u16x8*)Kp;  Kp += 64 * DD;
  u16x8 vv = *(const u16x8*)Vp;  Vp += 64 * DD;

  for (int kt = 0; kt < CHK; kt += 64) {
    __syncthreads();   // previous tile's PV reads done
    *(u16x8*)(sKb + kaddr) = kv;
    #pragma unroll
    for (int i = 0; i < 8; ++i) {
      int d = dq + i;
      int bb = ((d << 7) + (key_s << 1))
             ^ ((d & 7) << 4) ^ (((d >> 3) & 3) << 5);
      *(unsigned short*)(sVb + bb) = vv[i];
    }
    __syncthreads();   // staging visible
    if (kt + 64 < CHK) {          // issue next-tile loads; latency hidden below
      kv = *(const u16x8*)Kp;  Kp += 64 * DD;
      vv = *(const u16x8*)Vp;  Vp += 64 * DD;
    }

    f32x4 s[4];
    #pragma unroll
    for (int s4 = 0; s4 < 4; ++s4) {
      int key = s4 * 16 + l15;
      int ba = ((key << 6) + (l4 << 4)) ^ ((key & 7) << 4);
      bf16x8 kf = *(const bf16x8*)(sKb + ba);
      s[s4] = __builtin_amdgcn_mfma_f32_16x16x32_bf16(kf, qf, zero, 0, 0, 0);
    }
    float t0 = max3f(s[0][0], s[0][1], s[0][2]);
    float t1 = max3f(s[0][3], s[1][0], s[1][1]);
    float t2 = max3f(s[1][2], s[1][3], s[2][0]);
    float t3 = max3f(s[2][1], s[2][2], s[2][3]);
    float t4 = max3f(s[3][0], s[3][1], s[3][2]);
    float tmax = max3f(max3f(t0, t1, t2), fmaxf(t3, t4), s[3][3]);
    tmax = fmaxf(tmax, __shfl_xor(tmax, 16));
    tmax = fmaxf(tmax, __shfl_xor(tmax, 32));
    bool skip = __all(tmax - m <= 8.0f);
    float mnew = skip ? m : fmaxf(m, tmax);
    if (!skip) {
      float corr = __builtin_amdgcn_exp2f(m - mnew);
      l *= corr;
      oacc[0] *= corr;
      oacc[1] *= corr;
    }
    float psum = 0.0f;
    float p[4][4];
    #pragma unroll
    for (int s4 = 0; s4 < 4; ++s4)
      #pragma unroll
      for (int j = 0; j < 4; ++j) {
        p[s4][j] = __builtin_amdgcn_exp2f(s[s4][j] - mnew);
        psum += p[s4][j];
      }
    psum += __shfl_xor(psum, 16);
    psum += __shfl_xor(psum, 32);
    l += psum;
    m = mnew;
    // P write: r9 swizzle ^((l15&7)<<4); wave-private buffer -> no barrier
    #pragma unroll
    for (int s4 = 0; s4 < 4; ++s4) {
      uint2 pk = { cvtpk(p[s4][0], p[s4][1]), cvtpk(p[s4][2], p[s4][3]) };
      int bp = ((l15 << 7) + (s4 << 5) + (l4 << 3)) ^ ((l15 & 7) << 4);
      *(uint2*)(sPw + bp) = pk;
    }

    #pragma unroll
    for (int dh = 0; dh < 2; ++dh)
      #pragma unroll
      for (int kh = 0; kh < 2; ++kh) {
        int d = dh * 16 + l15;
        int ba = ((d << 7) + ((kh * 32 + l4 * 8) << 1))
               ^ ((d & 7) << 4) ^ (((d >> 3) & 3) << 5);
        bf16x8 vf = *(const bf16x8*)(sVb + ba);
        int bp = ((l15 << 7) + (kh << 6) + (l4 << 4)) ^ ((l15 & 7) << 4);
        bf16x8 pf = *(const bf16x8*)(sPw + bp);
        oacc[dh] = __builtin_amdgcn_mfma_f32_16x16x32_bf16(vf, pf, oacc[dh], 0, 0, 0);
      }
  }

  float inv = 1.0f / l;
  unsigned short* orow = O + base + (size_t)(q0 + l15) * DD;
  #pragma unroll
  for (int dh = 0; dh < 2; ++dh) {
    uint2 o2 = { cvtpk(oacc[dh][0] * inv, oacc[dh][1] * inv),
                 cvtpk(oacc[dh][2] * inv, oacc[dh][3] * inv) };
    *(uint2*)(orow + dh * 16 + l4 * 4) = o2;
  }
}

__global__ __launch_bounds__(256) void fill_kernel(float* p, long n, float v)
{
  long i = (long)blockIdx.x * 256 + threadIdx.x;
  if (i < n) p[i] = v;
}

extern "C" void kernel_launch(void* const* d_in, const int* in_sizes, int n_in,
                              void* d_out, int out_size, void* d_ws, size_t ws_size,
                              hipStream_t stream)
{
  const float* x     = (const float*)d_in[0];
  const int*   Acg_r = (const int*)d_in[1];
  const int*   Acg_c = (const int*)d_in[2];
  const float* Acg_v = (const float*)d_in[3];
  const int*   Ahy_r = (const int*)d_in[4];
  const int*   Ahy_c = (const int*)d_in[5];
  const float* Ahy_v = (const float*)d_in[6];
  const int*   Asg_r = (const int*)d_in[7];
  const int*   Asg_c = (const int*)d_in[8];
  const float* Asg_v = (const float*)d_in[9];
  const int*   Lcg_r = (const int*)d_in[10];
  const int*   Lcg_c = (const int*)d_in[11];
  const float* Lcg_v = (const float*)d_in[12];
  const int*   Lhy_r = (const int*)d_in[13];
  const int*   Lhy_c = (const int*)d_in[14];
  const float* Lhy_v = (const float*)d_in[15];
  const int*   Lsg_r = (const int*)d_in[16];
  const int*   Lsg_c = (const int*)d_in[17];
  const float* Lsg_v = (const float*)d_in[18];
  const float* cg_W  = (const float*)d_in[19];
  const float* cg_b  = (const float*)d_in[20];
  const float* hg_W  = (const float*)d_in[21];
  const float* hg_b  = (const float*)d_in[22];
  const float* sg_W  = (const float*)d_in[23];
  const float* sg_b  = (const float*)d_in[24];
  const float* snh_W = (const float*)d_in[25];
  const float* snh_b = (const float*)d_in[26];
  const float* snc_W = (const float*)d_in[27];
  const float* snc_b = (const float*)d_in[28];
  const float* sns_W = (const float*)d_in[29];
  const float* sns_b = (const float*)d_in[30];
  const float* spa_hyp_W  = (const float*)d_in[31];
  const float* spa_hyp_b  = (const float*)d_in[32];
  const float* spa_star_W = (const float*)d_in[33];
  const float* spa_star_b = (const float*)d_in[34];
  const float* spa_clq_W  = (const float*)d_in[35];
  const float* spa_clq_b  = (const float*)d_in[36];
  const float* spa_in_w   = (const float*)d_in[37];
  const float* spa_in_b   = (const float*)d_in[38];
  const float* spa_out_w  = (const float*)d_in[39];
  const float* spa_out_b  = (const float*)d_in[40];
  const float* spe_hyp_W  = (const float*)d_in[41];
  const float* spe_hyp_b  = (const float*)d_in[42];
  const float* spe_star_W = (const float*)d_in[43];
  const float* spe_star_b = (const float*)d_in[44];
  const float* spe_clq_W  = (const float*)d_in[45];
  const float* spe_clq_b  = (const float*)d_in[46];
  const float* spe_in_w   = (const float*)d_in[47];
  const float* spe_in_b   = (const float*)d_in[48];
  const float* spe_out_w  = (const float*)d_in[49];
  const float* spe_out_b  = (const float*)d_in[50];

  float* out = (float*)d_out;

  const size_t NF = (size_t)NN * DD;
  const size_t MF = (size_t)MM * DD;
  const size_t WELEMS  = 14u * 65536u;
  const size_t need = (14 * NF + 3 * MF) * 2
                    + (size_t)ETOT * 8
                    + ((size_t)3 * NN + 65536 + 256 + 4096) * 4
                    + ((size_t)ROWS_TOT + 1 + ROWS_TOT + 2048) * 4
                    + WELEMS * 2;

  auto fill = [&](float v) {
    long tot = (long)out_size;
    fill_kernel<<<dim3((unsigned)((tot + 255) / 256)), 256, 0, stream>>>(out, tot, v);
  };
  if (ws_size < need)                        { fill(12.0f); return; }
  if (n_in != 51)                            { fill(16.0f); return; }
  if (in_sizes[0] != NN * FD)                { fill(20.0f); return; }
  if (in_sizes[3] != NEN)                    { fill(24.0f); return; }
  if (in_sizes[9] != NEM)                    { fill(28.0f); return; }
  if (in_sizes[19] != 2 * FD * DD)           { fill(32.0f); return; }
  if (in_sizes[37] != 3 * DD * DD)           { fill(36.0f); return; }
  if (out_size != NN * 512 + NN * DD + EHN * DD) { fill(40.0f); return; }

  // ---- bf16 buffers ----
  unsigned short* Tcg = (unsigned short*)d_ws;
  unsigned short* Thy = Tcg + NF;
  unsigned short* Tsg = Thy + NF;
  unsigned short* Hcg = Tsg + NF;
  unsigned short* Hhy = Hcg + NF;
  unsigned short* Hsg = Hhy + NF;                // M
  unsigned short* Usg = Hsg + MF;                // M
  unsigned short* SG  = Usg + MF;                // M
  unsigned short* CG  = SG + MF;
  unsigned short* HG  = CG + NF;
  unsigned short* LH  = HG + NF;
  unsigned short* LC  = LH + NF;
  unsigned short* LS  = LC + NF;
  unsigned short* QH  = LS + NF;
  unsigned short* KH  = QH + NF;
  unsigned short* VH  = KH + NF;
  unsigned short* AOx = VH + NF;
  unsigned short* Ucg = Tcg;
  unsigned short* Uhy = Thy;
  unsigned short* Q2  = LH;
  unsigned short* K2  = LC;
  unsigned short* V2  = LS;
  unsigned short* AO1 = Hcg;
  unsigned short* AO2 = Hhy;
  (void)AOx;

  int2* epack = (int2*)(AOx + NF);
  float* fp = (float*)(epack + ETOT);
  float* rsAll = fp;           fp += 3 * NN;
  float* tmp256 = fp;          fp += 65536;
  float* tmpv = fp;            fp += 256;
  float* CB = fp;              fp += 4096;
  int* P    = (int*)fp;
  int* cnt  = P + ROWS_TOT + 1;
  int* bsum = cnt + ROWS_TOT;
  unsigned short* WB = (unsigned short*)(bsum + 2048);

  int* rp_cg  = P;
  int* rp_hy  = P + NN;
  int* rp_sg  = P + 2 * NN;
  int* rp_Lcg = P + 2 * NN + MM;
  int* rp_Lhy = P + 3 * NN + MM;
  int* rp_Lsg = P + 4 * NN + MM;
  float* rs_c = rsAll;
  float* rs_h = rsAll + NN;
  float* rs_s = rsAll + 2 * NN;

  auto wslot = [&](int s) { return WB + (size_t)s * 65536; };
  auto cb    = [&](int s) { return CB + (size_t)s * 256; };

  auto combine = [&](const float* Bw, const float* Aw, const float* ab,
                     const float* bb, unsigned short* Wc, float* bcp, float fs) {
    combine_w_kernel<<<dim3(256), 256, 0, stream>>>(Bw, Aw, ab, bb, Wc, bcp, fs);
  };
  auto combine3 = [&](const float* w3, const float* b3, const float* pW,
                      const float* pb, const float* sW, const float* sb,
                      unsigned short* Wc, float* cvecp, float* c0p, float fs) {
    mm256f_kernel<<<dim3(256), 256, 0, stream>>>(pW, sW, tmp256);
    mm256b_kernel<<<dim3(256), 256, 0, stream>>>(w3, tmp256, Wc, fs);
    mv256_kernel<<<dim3(1), 256, 0, stream>>>(pW, sb, nullptr, tmpv, 1.0f);
    mv256_kernel<<<dim3(1), 256, 0, stream>>>(w3, tmpv, nullptr, cvecp, fs);
    mv256_kernel<<<dim3(1), 256, 0, stream>>>(w3, pb, b3, c0p, fs);
  };

  const float fsQ = 0.17677669529663687f * 1.4426950408889634f;

  // ================= weight prep =================
  {
    CastJobs jobs;
    jobs.src[0] = cg_W;           jobs.dst[0] = wslot(0);  jobs.trans[0] = 1;
    jobs.src[1] = cg_W + FD * DD; jobs.dst[1] = wslot(1);  jobs.trans[1] = 1;
    jobs.src[2] = hg_W;           jobs.dst[2] = wslot(2);  jobs.trans[2] = 1;
    jobs.src[3] = hg_W + FD * DD; jobs.dst[3] = wslot(3);  jobs.trans[3] = 1;
    jobs.src[4] = sg_W;           jobs.dst[4] = wslot(4);  jobs.trans[4] = 1;
    jobs.src[5] = sg_W + FD * DD; jobs.dst[5] = wslot(5);  jobs.trans[5] = 1;
    jobs.src[6] = spa_out_w;      jobs.dst[6] = wslot(12); jobs.trans[6] = 0;
    jobs.src[7] = spe_out_w;      jobs.dst[7] = wslot(13); jobs.trans[7] = 0;
    cast_w8_kernel<<<dim3(8 * 256), 256, 0, stream>>>(jobs);
  }
  combine(spa_in_w,                spa_hyp_W,  spa_hyp_b,  spa_in_b,          wslot(6), cb(0), fsQ);
  combine(spa_in_w + DD * DD,      spa_star_W, spa_star_b, spa_in_b + DD,     wslot(7), cb(1), 1.0f);
  combine(spa_in_w + 2 * DD * DD,  spa_clq_W,  spa_clq_b,  spa_in_b + 2 * DD, wslot(8), cb(2), 1.0f);
  combine3(spe_in_w,               spe_in_b,            spe_hyp_W,  spe_hyp_b,  snh_W, snh_b, wslot(9),  cb(3), cb(4), fsQ);
  combine3(spe_in_w + DD * DD,     spe_in_b + DD,       spe_star_W, spe_star_b, snc_W, snc_b, wslot(10), cb(5), cb(6), 1.0f);
  combine3(spe_in_w + 2 * DD * DD, spe_in_b + 2 * DD,   spe_clq_W,  spe_clq_b,  sns_W, sns_b, wslot(11), cb(7), cb(8), 1.0f);

  // ================= batched CSR build =================
  {
    CooPtrs coo;
    coo.rw[0] = Acg_r; coo.cl[0] = Acg_c; coo.vl[0] = Acg_v;
    coo.rw[1] = Ahy_r; coo.cl[1] = Ahy_c; coo.vl[1] = Ahy_v;
    coo.rw[2] = Asg_r; coo.cl[2] = Asg_c; coo.vl[2] = Asg_v;
    coo.rw[3] = Lcg_r; coo.cl[3] = Lcg_c; coo.vl[3] = Lcg_v;
    coo.rw[4] = Lhy_r; coo.cl[4] = Lhy_c; coo.vl[4] = Lhy_v;
    coo.rw[5] = Lsg_r; coo.cl[5] = Lsg_c; coo.vl[5] = Lsg_v;
    hipMemsetAsync(cnt, 0, (size_t)ROWS_TOT * 4, stream);
    count_all_kernel<<<dim3(ETOT / 256), 256, 0, stream>>>(coo, cnt);
    scan1_kernel<<<dim3(ROWS_TOT / 256), 256, 0, stream>>>(cnt, bsum, ROWS_TOT);
    scan2_kernel<<<dim3(1), 256, 0, stream>>>(bsum, ROWS_TOT / 256);
    scan3_kernel<<<dim3(ROWS_TOT / 256), 256, 0, stream>>>(cnt, bsum, P, cnt, ROWS_TOT);
    fill_all_kernel<<<dim3(ETOT / 256), 256, 0, stream>>>(coo, P, cnt, epack);
    rowsum_all_kernel<<<dim3(3 * NN / 256), 256, 0, stream>>>(P, epack, rsAll);
  }

  // ================= expansion nets (batched x3) =================
  {
    Gemm3 g = {};
    for (int j = 0; j < 3; ++j) { g.A[j] = x; g.c0[j] = nullptr; g.rs[j] = nullptr; }
    g.W[0] = wslot(0); g.out[0] = Tcg;
    g.W[1] = wslot(2); g.out[1] = Thy;
    g.W[2] = wslot(4); g.out[2] = Tsg;
    g.bs1 = 768; g.bs2 = 1536; g.btot = 2304;
    gemm3_kernel<0><<<dim3(2304), 256, 0, stream>>>(g);
  }
  {
    Spmm3 s = {};
    s.rowptr[0] = rp_cg; s.X[0] = Tcg; s.Y[0] = Hcg; s.Y2[0] = nullptr; s.bias[0] = cg_b; s.src_rows[0] = NN;
    s.rowptr[1] = rp_hy; s.X[1] = Thy; s.Y[1] = Hhy; s.Y2[1] = nullptr; s.bias[1] = hg_b; s.src_rows[1] = NN;
    s.rowptr[2] = rp_sg; s.X[2] = Tsg; s.Y[2] = Hsg; s.Y2[2] = nullptr; s.bias[2] = sg_b; s.src_rows[2] = NN;
    s.bs1 = NN / 4; s.bs2 = 2 * (NN / 4);
    spmm3_kernel<<<dim3(2 * (NN / 4) + MM / 4), 256, 0, stream>>>(s, epack, 1);
  }
  {
    Gemm3 g = {};
    g.A[0] = Hcg; g.W[0] = wslot(1); g.out[0] = Ucg;
    g.A[1] = Hhy; g.W[1] = wslot(3); g.out[1] = Uhy;
    g.A[2] = Hsg; g.W[2] = wslot(5); g.out[2] = Usg;
    for (int j = 0; j < 3; ++j) { g.c0[j] = nullptr; g.rs[j] = nullptr; }
    g.bs1 = NN / 64; g.bs2 = 2 * (NN / 64); g.btot = 2 * (NN / 64) + MM / 64;
    gemm3_kernel<1><<<dim3(2 * (NN / 64) + MM / 64), 256, 0, stream>>>(g);
  }
  {
    Spmm3 s = {};
    s.rowptr[0] = rp_cg; s.X[0] = Ucg; s.Y[0] = CG; s.Y2[0] = nullptr; s.bias[0] = cg_b + DD; s.src_rows[0] = NN;
    s.rowptr[1] = rp_hy; s.X[1] = Uhy; s.Y[1] = HG; s.Y2[1] = nullptr; s.bias[1] = hg_b + DD; s.src_rows[1] = NN;
    s.rowptr[2] = rp_sg; s.X[2] = Usg; s.Y[2] = SG; s.Y2[2] = out + (size_t)NN * 512; s.bias[2] = sg_b + DD; s.src_rows[2] = MM;
    s.bs1 = NN / 4; s.bs2 = 2 * (NN / 4);
    spmm3_kernel<<<dim3(2 * (NN / 4) + MM / 4), 256, 0, stream>>>(s, epack, 0);
  }
  {
    Spmm3 s = {};
    s.rowptr[0] = rp_Lhy; s.X[0] = HG; s.Y[0] = LH; s.Y2[0] = nullptr; s.bias[0] = nullptr; s.src_rows[0] = NN;
    s.rowptr[1] = rp_Lcg; s.X[1] = CG; s.Y[1] = LC; s.Y2[1] = nullptr; s.bias[1] = nullptr; s.src_rows[1] = NN;
    s.rowptr[2] = rp_Lsg; s.X[2] = SG; s.Y[2] = LS; s.Y2[2] = nullptr; s.bias[2] = nullptr; s.src_rows[2] = MM;
    s.bs1 = NN / 4; s.bs2 = 2 * (NN / 4);
    spmm3_kernel<<<dim3(3 * (NN / 4)), 256, 0, stream>>>(s, epack, 0);
  }

  // ================= both MHAs =================
  {  // spectral QKV: LH/LC/LS -> QH/KH/VH
    Gemm3 g = {};
    g.A[0] = LH; g.W[0] = wslot(9);  g.c0[0] = cb(4); g.rs[0] = rs_h; g.cvec[0] = cb(3); g.out[0] = QH;
    g.A[1] = LC; g.W[1] = wslot(10); g.c0[1] = cb(6); g.rs[1] = rs_c; g.cvec[1] = cb(5); g.out[1] = KH;
    g.A[2] = LS; g.W[2] = wslot(11); g.c0[2] = cb(8); g.rs[2] = rs_s; g.cvec[2] = cb(7); g.out[2] = VH;
    g.bs1 = 768; g.bs2 = 1536; g.btot = 2304;
    gemm3_kernel<1><<<dim3(2304), 256, 0, stream>>>(g);
  }
  {  // spatial QKV: HG/CG/SG -> Q2/K2/V2 (reuse dead LH/LC/LS)
    Gemm3 g = {};
    g.A[0] = HG; g.W[0] = wslot(6); g.c0[0] = cb(0); g.rs[0] = nullptr; g.out[0] = Q2;
    g.A[1] = CG; g.W[1] = wslot(7); g.c0[1] = cb(1); g.rs[1] = nullptr; g.out[1] = K2;
    g.A[2] = SG; g.W[2] = wslot(8); g.c0[2] = cb(2); g.rs[2] = nullptr; g.out[2] = V2;
    g.bs1 = 768; g.bs2 = 1536; g.btot = 2304;
    gemm3_kernel<1><<<dim3(2304), 256, 0, stream>>>(g);
  }
  attn2_kernel<<<dim3(12288), 256, 0, stream>>>(QH, KH, VH, AO1,
                                                Q2, K2, V2, AO2);
  gemmout2_kernel<<<dim3(2 * (NN / 64)), 256, 0, stream>>>(
      AO1, wslot(13), spe_out_b,       // job0: spectral -> taa cols 256..511
      AO2, wslot(12), spa_out_b,       // job1: spatial  -> taa cols 0..255
      out);
}